// Round 6
// baseline (743.101 us; speedup 1.0000x reference)
//
#include <hip/hip_runtime.h>
#include <hip/hip_cooperative_groups.h>
#include <stdint.h>

namespace cg = cooperative_groups;

#define N_P 100000
#define N_D 50000
#define NE  600000
#define F   128
#define FP  136   // padded LDS/global row stride (272B = 17*16B: 16B-aligned, 2-way-free banks)

// counting-sort build params (u16-packed hist, HPH=4, NCHK=16)
#define NCHK   16
#define CHKE   37504                 // edges per chunk (mult of 4); last chunk = 37440
#define HPH    4                     // hist partitions (u16-packed -> 50 KB LDS)
#define HPS    8                     // scatter partitions (int cursors -> 50 KB LDS)
#define NBLD   256                   // build grid (cooperative)
#define NBA    ((N_D + 511)/512)     // 98  scan tiles (pd)
#define NBB    ((N_P + 511)/512)     // 196 scan tiles (dp)
// hist layout (ints): A0 pd_src[16][N_P] | A1 pd_dst[16][N_D] | A2 dp_src[16][N_D] | A3 dp_dst[16][N_P]
#define HOFS_A0 ((size_t)0)
#define HOFS_A1 ((size_t)NCHK*N_P)
#define HOFS_A2 ((size_t)NCHK*N_P + (size_t)NCHK*N_D)
#define HOFS_A3 ((size_t)NCHK*N_P + (size_t)2*NCHK*N_D)
// convert work units ("original blocks" of 256 threads)
#define CVT_TOT (6 + (N_P+N_D)*F/4/256)   // 6 + 18750 = 18756
#define CVT_A   6252
#define CVT_B   12504

typedef __attribute__((ext_vector_type(8))) __bf16 bf16x8;
typedef __attribute__((ext_vector_type(4))) float  f32x4;
typedef unsigned int __attribute__((ext_vector_type(4))) u32x4;

static __device__ __forceinline__ float bf2f(uint16_t u){
  union{float f;uint32_t i;} v; v.i = ((uint32_t)u)<<16; return v.f;
}
static __device__ __forceinline__ uint16_t f2bf(float f){
  union{float f;uint32_t i;} v; v.f = f;
  uint32_t i = v.i;
  uint32_t r = i + 0x7fffu + ((i>>16)&1u);   // round-to-nearest-even
  return (uint16_t)(r>>16);
}
// non-temporal 16B load (evict-first: gather rows have no L1 reuse; keep L1
// MSHRs/lines for col/off streams)
static __device__ __forceinline__ uint4 ld_nt_u4(const uint16_t* p){
  u32x4 v = __builtin_nontemporal_load((const u32x4*)p);
  uint4 r; r.x = v.x; r.y = v.y; r.z = v.z; r.w = v.w; return r;
}

// ---- convert work unit: ob<6 = weight transpose + sentinel; else features ----
static __device__ __forceinline__ void convert_ob(
    int ob, int t,
    const float4* __restrict__ hp, const float4* __restrict__ hd,
    const float* __restrict__ rs_po, const float* __restrict__ rs_do,
    uint2* __restrict__ P0, uint2* __restrict__ D0,
    const float* w0,const float* w1,const float* w2,
    const float* w3,const float* w4,const float* w5,
    uint16_t* __restrict__ wt,
    uint16_t* z0, uint16_t* z1, uint16_t* z2,
    uint16_t* z3, uint16_t* z4, uint16_t* z5)
{
  if (ob < 6){
    const float* W; uint16_t* Z;
    switch(ob){ case 0:W=w0;Z=z0;break; case 1:W=w1;Z=z1;break; case 2:W=w2;Z=z2;break;
                case 3:W=w3;Z=z3;break; case 4:W=w4;Z=z4;break; default:W=w5;Z=z5; }
    uint16_t* T = wt + ob*F*FP;
    for (int idx = t; idx < F*F; idx += 256){
      int k = idx >> 7, j = idx & 127;
      T[j*FP + k] = f2bf(W[idx]);
    }
    if (t < F) Z[t] = 0;   // sentinel zero row
    return;
  }
  int i = (ob - 6)*256 + t;
  const int nP4 = N_P*F/4, nD4 = N_D*F/4;
  if (i < nP4){
    float4 v = hp[i]; float s = rs_po[i >> 5];
    uint2 r;
    r.x = ((uint32_t)f2bf(v.y*s)<<16) | f2bf(v.x*s);
    r.y = ((uint32_t)f2bf(v.w*s)<<16) | f2bf(v.z*s);
    P0[i] = r;
  } else {
    int j = i - nP4;
    if (j < nD4){
      float4 v = hd[j]; float s = rs_do[j >> 5];
      uint2 r;
      r.x = ((uint32_t)f2bf(v.y*s)<<16) | f2bf(v.x*s);
      r.y = ((uint32_t)f2bf(v.w*s)<<16) | f2bf(v.z*s);
      D0[j] = r;
    }
  }
}

// ================== R6: ONE cooperative build kernel =========================
// P1 hist -> P2 sumdeg+rs -> P3 scan-partials ∥ convert-A -> P4 partial-scan
// (block 0) ∥ convert-B -> P5 scan-apply ∥ convert-C -> P6 scatter.
// Replaces 7 dispatches (launch gaps + underfilled scan kernels); the tiny
// scan phases hide under the 115 MB convert stream. 256 blocks x 512 thr,
// 50 KB LDS -> 3 blocks/CU; full co-residency (1 blk/CU needed) guaranteed.
__global__ __launch_bounds__(512) void k_build(
    const int* __restrict__ pd_src, const int* __restrict__ pd_dst,
    const int* __restrict__ dp_src, const int* __restrict__ dp_dst,
    int* __restrict__ hist,
    int* __restrict__ cnt_d_in, int* __restrict__ cnt_p_in,
    float* __restrict__ rs_p_out, float* __restrict__ rs_p_in,
    float* __restrict__ rs_d_out, float* __restrict__ rs_d_in,
    int* __restrict__ bsums,
    int* __restrict__ off_pd, int* __restrict__ off_dp,
    int* __restrict__ col_pd, int* __restrict__ col_dp,
    const float4* __restrict__ hp, const float4* __restrict__ hd,
    uint2* __restrict__ P0, uint2* __restrict__ D0,
    const float* w0,const float* w1,const float* w2,
    const float* w3,const float* w4,const float* w5,
    uint16_t* __restrict__ wt,
    uint16_t* z0, uint16_t* z1, uint16_t* z2,
    uint16_t* z3, uint16_t* z4, uint16_t* z5)
{
  __shared__ union {
    uint32_t cnt[(N_P/HPH)/2];   // P1: u16-packed hist  (50 KB)
    int      base[N_P/HPS];      // P6: scatter cursors  (50 KB)
    int      sh512[512];         // P5: apply scan
    int      sh256[256];         // P4: partial scan
  } sm;
  __shared__ int red2[8];
  cg::grid_group grid = cg::this_grid();
  const int t = threadIdx.x;
  const int b = blockIdx.x;

  // ---------------- P1: per-(array, part, chunk) LDS histogram --------------
  {
    const int arr = b >> 6, part = (b >> 4) & 3, chunk = b & 15;
    const int* src; int N; size_t hofs;
    switch(arr){
      case 0:  src = pd_src; N = N_P; hofs = HOFS_A0; break;
      case 1:  src = pd_dst; N = N_D; hofs = HOFS_A1; break;
      case 2:  src = dp_src; N = N_D; hofs = HOFS_A2; break;
      default: src = dp_dst; N = N_P; hofs = HOFS_A3; break;
    }
    const int PART = N / HPH;
    const int nw   = PART >> 1;
    const int lo   = part * PART;
    for (int i = t; i < nw; i += 512) sm.cnt[i] = 0;
    __syncthreads();
    const int e0 = chunk*CHKE, e1 = min(e0 + CHKE, NE);
    const uint4* s4 = (const uint4*)(src + e0);
    const int n4 = (e1 - e0) >> 2;
    for (int i = t; i < n4; i += 512){
      uint4 v = s4[i];
      int a0 = (int)v.x - lo, a1 = (int)v.y - lo, a2 = (int)v.z - lo, a3 = (int)v.w - lo;
      if ((unsigned)a0 < (unsigned)PART) atomicAdd(&sm.cnt[a0>>1], 1u << ((a0&1)<<4));
      if ((unsigned)a1 < (unsigned)PART) atomicAdd(&sm.cnt[a1>>1], 1u << ((a1&1)<<4));
      if ((unsigned)a2 < (unsigned)PART) atomicAdd(&sm.cnt[a2>>1], 1u << ((a2&1)<<4));
      if ((unsigned)a3 < (unsigned)PART) atomicAdd(&sm.cnt[a3>>1], 1u << ((a3&1)<<4));
    }
    __syncthreads();
    int* out = hist + hofs + (size_t)chunk*N + lo;
    for (int i = t; i < nw; i += 512){
      uint32_t wv = sm.cnt[i];
      out[2*i]   = (int)(wv & 0xffffu);
      out[2*i+1] = (int)(wv >> 16);
    }
  }
  grid.sync();

  // ---------------- P2: chunk-prefix (dst arrays) + degrees + rsqrt ---------
  {
    const int gtid = b*512 + t;
    const int T0 = N_P, T1 = N_P+N_D, T2 = N_P+2*N_D, T3 = 2*N_P+2*N_D;
    for (int w = gtid; w < T3; w += NBLD*512){
      int arr, idx;
      if      (w < T0){ arr = 0; idx = w; }
      else if (w < T1){ arr = 1; idx = w - T0; }
      else if (w < T2){ arr = 2; idx = w - T1; }
      else            { arr = 3; idx = w - T2; }
      int N; size_t hofs; bool pre;
      switch(arr){
        case 0:  N = N_P; hofs = HOFS_A0; pre = false; break;
        case 1:  N = N_D; hofs = HOFS_A1; pre = true;  break;
        case 2:  N = N_D; hofs = HOFS_A2; pre = false; break;
        default: N = N_P; hofs = HOFS_A3; pre = true;  break;
      }
      int* basep = hist + hofs + idx;
      int run = 0;
      if (pre){
        #pragma unroll 4
        for (int c = 0; c < NCHK; ++c){
          int v = basep[(size_t)c*N]; basep[(size_t)c*N] = run; run += v;
        }
      } else {
        #pragma unroll 4
        for (int c = 0; c < NCHK; ++c) run += basep[(size_t)c*N];
      }
      float rs = rsqrtf((float)max(run, 1));
      switch(arr){
        case 0:  rs_p_out[idx] = rs; break;
        case 1:  cnt_d_in[idx] = run; rs_d_in[idx] = rs; break;
        case 2:  rs_d_out[idx] = rs; break;
        default: cnt_p_in[idx] = run; rs_p_in[idx] = rs; break;
      }
    }
  }
  grid.sync();

  // ---------------- P3: scan tile partials  ∥  convert-A --------------------
  {
    for (int tb = b; tb < NBA+NBB; tb += NBLD){
      const int* in; int n, bi, slot;
      if (tb < NBA){ in = cnt_d_in; n = N_D; bi = tb;       slot = bi; }
      else         { in = cnt_p_in; n = N_P; bi = tb - NBA; slot = 256 + bi; }
      int i = bi*512 + t;
      int v = (i < n) ? in[i] : 0;
      #pragma unroll
      for (int o = 32; o; o >>= 1) v += __shfl_down(v, o, 64);
      if ((t & 63) == 0) red2[t >> 6] = v;
      __syncthreads();
      if (t == 0){ int s = 0; for (int k = 0; k < 8; ++k) s += red2[k]; bsums[slot] = s; }
      __syncthreads();
    }
    for (int p0 = 0 + b*2; p0 < CVT_A; p0 += NBLD*2){
      int ob = p0 + (t >> 8);
      if (ob < CVT_A)
        convert_ob(ob, t & 255, hp, hd, rs_p_out, rs_d_out, P0, D0,
                   w0,w1,w2,w3,w4,w5, wt, z0,z1,z2,z3,z4,z5);
    }
  }
  grid.sync();

  // ---------------- P4: block 0 scans partials  ∥  convert-B ----------------
  if (b == 0){
    for (int seg = 0; seg < 2; ++seg){
      int nb = seg ? NBB : NBA;
      int* p = bsums + seg*256;
      int v = 0;
      if (t < 256){ v = (t < nb) ? p[t] : 0; sm.sh256[t] = v; }
      __syncthreads();
      for (int ofs = 1; ofs < 256; ofs <<= 1){
        int u2 = 0;
        if (t < 256 && t >= ofs) u2 = sm.sh256[t-ofs];
        __syncthreads();
        if (t < 256) sm.sh256[t] += u2;
        __syncthreads();
      }
      if (t < nb) p[t] = sm.sh256[t] - v;   // exclusive
      __syncthreads();
    }
  } else {
    for (int p0 = CVT_A + (b-1)*2; p0 < CVT_B; p0 += (NBLD-1)*2){
      int ob = p0 + (t >> 8);
      if (ob < CVT_B)
        convert_ob(ob, t & 255, hp, hd, rs_p_out, rs_d_out, P0, D0,
                   w0,w1,w2,w3,w4,w5, wt, z0,z1,z2,z3,z4,z5);
    }
  }
  grid.sync();

  // ---------------- P5: scan apply (write off)  ∥  convert-C ----------------
  {
    for (int tb = b; tb < NBA+NBB; tb += NBLD){
      const int* in; int n, bi; int* outp; int base;
      if (tb < NBA){ in = cnt_d_in; n = N_D; bi = tb;       outp = off_pd; base = bsums[bi]; }
      else         { in = cnt_p_in; n = N_P; bi = tb - NBA; outp = off_dp; base = bsums[256+bi]; }
      int i = bi*512 + t;
      int v = (i < n) ? in[i] : 0;
      sm.sh512[t] = v; __syncthreads();
      for (int ofs = 1; ofs < 512; ofs <<= 1){
        int u2 = (t >= ofs) ? sm.sh512[t-ofs] : 0; __syncthreads();
        sm.sh512[t] += u2; __syncthreads();
      }
      if (i < n) outp[i] = base + sm.sh512[t] - v;
      __syncthreads();
    }
    if (b == 0 && t == 0){ off_pd[N_D] = NE; off_dp[N_P] = NE; }
    for (int p0 = CVT_B + b*2; p0 < CVT_TOT; p0 += NBLD*2){
      int ob = p0 + (t >> 8);
      if (ob < CVT_TOT)
        convert_ob(ob, t & 255, hp, hd, rs_p_out, rs_d_out, P0, D0,
                   w0,w1,w2,w3,w4,w5, wt, z0,z1,z2,z3,z4,z5);
    }
  }
  grid.sync();

  // ---------------- P6: scatter (LDS cursors) -------------------------------
  {
    const int gph = b >> 7, part = (b >> 4) & 7, chunk = b & 15;
    const int* dsts; const int* srcs; const int* off; int* col; int N; size_t hofs;
    if (gph == 0){ dsts = pd_dst; srcs = pd_src; off = off_pd; col = col_pd; N = N_D; hofs = HOFS_A1; }
    else         { dsts = dp_dst; srcs = dp_src; off = off_dp; col = col_dp; N = N_P; hofs = HOFS_A3; }
    const int PART = N / HPS;
    const int lo = part * PART;
    const int* hc   = hist + hofs + (size_t)chunk*N + lo;
    const int* offp = off + lo;
    for (int i = t; i < PART; i += 512) sm.base[i] = offp[i] + hc[i];
    __syncthreads();
    const int e0 = chunk*CHKE, e1 = min(e0 + CHKE, NE);
    const uint4* d4 = (const uint4*)(dsts + e0);
    const int n4 = (e1 - e0) >> 2;
    for (int i = t; i < n4; i += 512){
      uint4 d = d4[i];
      int a0 = (int)d.x - lo, a1 = (int)d.y - lo, a2 = (int)d.z - lo, a3 = (int)d.w - lo;
      int e = e0 + 4*i;
      if ((unsigned)a0 < (unsigned)PART){ int p = atomicAdd(&sm.base[a0], 1); col[p] = srcs[e+0]; }
      if ((unsigned)a1 < (unsigned)PART){ int p = atomicAdd(&sm.base[a1], 1); col[p] = srcs[e+1]; }
      if ((unsigned)a2 < (unsigned)PART){ int p = atomicAdd(&sm.base[a2], 1); col[p] = srcs[e+2]; }
      if ((unsigned)a3 < (unsigned)PART){ int p = atomicAdd(&sm.base[a3], 1); col[p] = srcs[e+3]; }
    }
  }
}

// ================ fallback discrete build kernels (R4, proven) ==============
__global__ __launch_bounds__(512) void k_hist(
    const int* __restrict__ pd_src, const int* __restrict__ pd_dst,
    const int* __restrict__ dp_src, const int* __restrict__ dp_dst,
    int* __restrict__ hist){
  __shared__ uint32_t cnt[(N_P/HPH)/2];
  const int b = blockIdx.x;
  const int arr = b >> 6, part = (b >> 4) & 3, chunk = b & 15;
  const int* src; int N; size_t hofs;
  switch(arr){
    case 0:  src = pd_src; N = N_P; hofs = HOFS_A0; break;
    case 1:  src = pd_dst; N = N_D; hofs = HOFS_A1; break;
    case 2:  src = dp_src; N = N_D; hofs = HOFS_A2; break;
    default: src = dp_dst; N = N_P; hofs = HOFS_A3; break;
  }
  const int PART = N / HPH;
  const int nw   = PART >> 1;
  const int lo   = part * PART;
  for (int i = threadIdx.x; i < nw; i += 512) cnt[i] = 0;
  __syncthreads();
  const int e0 = chunk*CHKE, e1 = min(e0 + CHKE, NE);
  const uint4* s4 = (const uint4*)(src + e0);
  const int n4 = (e1 - e0) >> 2;
  for (int i = threadIdx.x; i < n4; i += 512){
    uint4 v = s4[i];
    int a0 = (int)v.x - lo, a1 = (int)v.y - lo, a2 = (int)v.z - lo, a3 = (int)v.w - lo;
    if ((unsigned)a0 < (unsigned)PART) atomicAdd(&cnt[a0>>1], 1u << ((a0&1)<<4));
    if ((unsigned)a1 < (unsigned)PART) atomicAdd(&cnt[a1>>1], 1u << ((a1&1)<<4));
    if ((unsigned)a2 < (unsigned)PART) atomicAdd(&cnt[a2>>1], 1u << ((a2&1)<<4));
    if ((unsigned)a3 < (unsigned)PART) atomicAdd(&cnt[a3>>1], 1u << ((a3&1)<<4));
  }
  __syncthreads();
  int* out = hist + hofs + (size_t)chunk*N + lo;
  for (int i = threadIdx.x; i < nw; i += 512){
    uint32_t w = cnt[i];
    out[2*i]   = (int)(w & 0xffffu);
    out[2*i+1] = (int)(w >> 16);
  }
}

__global__ void k_sumdeg(int* __restrict__ hist,
                         int* __restrict__ cnt_d_in, int* __restrict__ cnt_p_in,
                         float* __restrict__ rs_p_out, float* __restrict__ rs_p_in,
                         float* __restrict__ rs_d_out, float* __restrict__ rs_d_in){
  const int idx = blockIdx.x*256 + threadIdx.x;
  const int arr = blockIdx.y;
  int N; size_t hofs; bool pre;
  switch(arr){
    case 0:  N = N_P; hofs = HOFS_A0; pre = false; break;
    case 1:  N = N_D; hofs = HOFS_A1; pre = true;  break;
    case 2:  N = N_D; hofs = HOFS_A2; pre = false; break;
    default: N = N_P; hofs = HOFS_A3; pre = true;  break;
  }
  if (idx >= N) return;
  int* base = hist + hofs + idx;
  int run = 0;
  if (pre){
    #pragma unroll 4
    for (int c = 0; c < NCHK; ++c){
      int v = base[(size_t)c*N]; base[(size_t)c*N] = run; run += v;
    }
  } else {
    #pragma unroll 4
    for (int c = 0; c < NCHK; ++c) run += base[(size_t)c*N];
  }
  float rs = rsqrtf((float)max(run, 1));
  switch(arr){
    case 0:  rs_p_out[idx] = rs; break;
    case 1:  cnt_d_in[idx] = run; rs_d_in[idx] = rs; break;
    case 2:  rs_d_out[idx] = rs; break;
    default: cnt_p_in[idx] = run; rs_p_in[idx] = rs; break;
  }
}

__global__ void k_scan1(const int* __restrict__ cA, int nA,
                        const int* __restrict__ cB, int nB,
                        int* __restrict__ bsums, int nbA){
  __shared__ int red[8];
  int b = blockIdx.x, t = threadIdx.x;
  const int* in; int n, bi, slot;
  if (b < nbA){ in = cA; n = nA; bi = b;       slot = bi; }
  else        { in = cB; n = nB; bi = b - nbA; slot = 256 + bi; }
  int i = bi*512 + t;
  int v = (i < n) ? in[i] : 0;
  #pragma unroll
  for (int o = 32; o; o >>= 1) v += __shfl_down(v, o, 64);
  if ((t & 63) == 0) red[t >> 6] = v;
  __syncthreads();
  if (t == 0){ int s = 0; for (int k = 0; k < 8; ++k) s += red[k]; bsums[slot] = s; }
}

__global__ void k_scan2(int* bsums, int nbA, int nbB){
  __shared__ int sh[256];
  int seg = blockIdx.x, t = threadIdx.x;
  int nb = seg ? nbB : nbA;
  int* p = bsums + seg*256;
  int v = (t < nb) ? p[t] : 0;
  sh[t] = v; __syncthreads();
  for (int ofs = 1; ofs < 256; ofs <<= 1){
    int u = (t >= ofs) ? sh[t-ofs] : 0; __syncthreads();
    sh[t] += u; __syncthreads();
  }
  if (t < nb) p[t] = sh[t] - v;   // exclusive
}

__global__ void k_scan3(const int* __restrict__ cA, int nA,
                        const int* __restrict__ cB, int nB,
                        const int* __restrict__ bsums, int nbA,
                        int* __restrict__ offA, int* __restrict__ offB){
  __shared__ int sh[512];
  int b = blockIdx.x, t = threadIdx.x;
  const int* in; int n, bi; int* out; int base;
  if (b < nbA){ in = cA; n = nA; bi = b;       out = offA; base = bsums[bi]; }
  else        { in = cB; n = nB; bi = b - nbA; out = offB; base = bsums[256+bi]; }
  int i = bi*512 + t;
  int v = (i < n) ? in[i] : 0;
  sh[t] = v; __syncthreads();
  for (int ofs = 1; ofs < 512; ofs <<= 1){
    int u = (t >= ofs) ? sh[t-ofs] : 0; __syncthreads();
    sh[t] += u; __syncthreads();
  }
  if (i < n) out[i] = base + sh[t] - v;
  if (b == 0 && t == 0){ offA[nA] = NE; offB[nB] = NE; }
}

__global__ __launch_bounds__(512) void k_scatter(
    const int* __restrict__ pd_src, const int* __restrict__ pd_dst,
    const int* __restrict__ dp_src, const int* __restrict__ dp_dst,
    const int* __restrict__ off_pd, const int* __restrict__ off_dp,
    const int* __restrict__ hist,
    int* __restrict__ col_pd, int* __restrict__ col_dp){
  __shared__ int base[N_P/HPS];
  const int b = blockIdx.x;
  const int gph = b >> 7, part = (b >> 4) & 7, chunk = b & 15;
  const int* dsts; const int* srcs; const int* off; int* col; int N; size_t hofs;
  if (gph == 0){ dsts = pd_dst; srcs = pd_src; off = off_pd; col = col_pd; N = N_D; hofs = HOFS_A1; }
  else         { dsts = dp_dst; srcs = dp_src; off = off_dp; col = col_dp; N = N_P; hofs = HOFS_A3; }
  const int PART = N / HPS;
  const int lo = part * PART;
  const int* hc   = hist + hofs + (size_t)chunk*N + lo;
  const int* offp = off + lo;
  for (int i = threadIdx.x; i < PART; i += 512) base[i] = offp[i] + hc[i];
  __syncthreads();
  const int e0 = chunk*CHKE, e1 = min(e0 + CHKE, NE);
  const uint4* d4 = (const uint4*)(dsts + e0);
  const int n4 = (e1 - e0) >> 2;
  for (int i = threadIdx.x; i < n4; i += 512){
    uint4 d = d4[i];
    int a0 = (int)d.x - lo, a1 = (int)d.y - lo, a2 = (int)d.z - lo, a3 = (int)d.w - lo;
    int e = e0 + 4*i;
    if ((unsigned)a0 < (unsigned)PART){ int p = atomicAdd(&base[a0], 1); col[p] = srcs[e+0]; }
    if ((unsigned)a1 < (unsigned)PART){ int p = atomicAdd(&base[a1], 1); col[p] = srcs[e+1]; }
    if ((unsigned)a2 < (unsigned)PART){ int p = atomicAdd(&base[a2], 1); col[p] = srcs[e+2]; }
    if ((unsigned)a3 < (unsigned)PART){ int p = atomicAdd(&base[a3], 1); col[p] = srcs[e+3]; }
  }
}

__global__ void k_convert(const float4* __restrict__ hp, const float4* __restrict__ hd,
                          const float* __restrict__ rs_po, const float* __restrict__ rs_do,
                          uint2* __restrict__ P0, uint2* __restrict__ D0,
                          const float* w0,const float* w1,const float* w2,
                          const float* w3,const float* w4,const float* w5,
                          uint16_t* __restrict__ wt,
                          uint16_t* z0, uint16_t* z1, uint16_t* z2,
                          uint16_t* z3, uint16_t* z4, uint16_t* z5){
  convert_ob(blockIdx.x, threadIdx.x, hp, hd, rs_po, rs_do, P0, D0,
             w0,w1,w2,w3,w4,w5, wt, z0,z1,z2,z3,z4,z5);
}

// ---------------- fused gconv PAIR (R1 structure, proven) -------------------
// Gather: wave = 4 groups of 16 lanes; group g owns a row, lane l holds
// features [8l,8l+8). Broadcast all 16 col indices of the batch up front,
// issue ALL 8 (16 when deg>8) uint4 gather loads into explicit register
// arrays, THEN accumulate. Gather loads NON-TEMPORAL (no L1 reuse). R2's
// dual-stream attempt regressed — do not re-add.
template<int OUT_MODE>
__global__ __launch_bounds__(256, 4) void k_gconv2(
    const uint16_t* __restrict__ xA, const int* __restrict__ offAp, const int* __restrict__ colA,
    const float* __restrict__ rsA, const uint16_t* __restrict__ WtA, const float* __restrict__ biasA,
    const float* __restrict__ rsnA, void* __restrict__ outA, int ndA, int nsA, int nblkA,
    const uint16_t* __restrict__ xB, const int* __restrict__ offBp, const int* __restrict__ colB,
    const float* __restrict__ rsB, const uint16_t* __restrict__ WtB, const float* __restrict__ biasB,
    const float* __restrict__ rsnB, void* __restrict__ outB, int ndB, int nsB)
{
  __shared__ uint16_t m_lds[64*FP];    // 17408 B
  const int tid  = threadIdx.x;
  const int lane = tid & 63;
  const int wv   = tid >> 6;

  const uint16_t* x; const int* off; const int* col; const float* rs_in;
  const uint16_t* Wt; const float* bias; const float* rs_next; void* outp;
  int n_dst, zrow, bid;
  if ((int)blockIdx.x < nblkA){
    x = xA; off = offAp; col = colA; rs_in = rsA; Wt = WtA; bias = biasA;
    rs_next = rsnA; outp = outA; n_dst = ndA; zrow = nsA; bid = blockIdx.x;
  } else {
    x = xB; off = offBp; col = colB; rs_in = rsB; Wt = WtB; bias = biasB;
    rs_next = rsnB; outp = outB; n_dst = ndB; zrow = nsB; bid = blockIdx.x - nblkA;
  }

  // ---- aggregation ----
  const int row0 = bid*64 + wv*16;
  const int g    = lane >> 4;     // group
  const int l    = lane & 15;     // lane in group; features [8l, 8l+8)
  const uint16_t* xl = x + l*8;   // lane-fixed feature slice base

  int e0a[4], e1a[4], cva[4];
  #pragma unroll
  for (int i = 0; i < 4; ++i){
    int r = row0 + i*4 + g;
    bool rv = r < n_dst;
    e0a[i] = rv ? off[r]   : 0;
    e1a[i] = rv ? off[r+1] : 0;
  }
  #pragma unroll
  for (int i = 0; i < 4; ++i){
    int last = (e1a[i] > 0) ? e1a[i]-1 : 0;
    int idx  = e0a[i] + l;
    cva[i] = col[idx < e1a[i] ? idx : last];   // hoisted first batch (4 loads in flight)
  }

  #pragma unroll
  for (int i = 0; i < 4; ++i){
    int e0 = e0a[i], e1 = e1a[i];
    int cv = cva[i];
    float a0=0.f,a1=0.f,a2=0.f,a3=0.f,a4=0.f,a5=0.f,a6=0.f,a7=0.f;
    for (int e = e0; e < e1; e += 16){
      // prefetch next batch of col indices (clamped; harmless L1 re-read)
      int nidx = e + 16 + l;
      int ncv  = col[nidx < e1 ? nidx : e1-1];
      int cnt  = e1 - e;
      const bool more = (cnt > 8);
      // broadcast col indices for the whole batch up front (VALU/LDS only)
      int cb[16];
      #pragma unroll
      for (int q = 0; q < 8; ++q) cb[q] = __shfl(cv, g*16 + q, 64);
      if (more){
        #pragma unroll
        for (int q = 8; q < 16; ++q) cb[q] = __shfl(cv, g*16 + q, 64);
      }
      // issue ALL gather loads before any accumulation (max MLP)
      uint4 u[8], w[8];
      #pragma unroll
      for (int q = 0; q < 8; ++q){
        int c = (q < cnt) ? cb[q] : zrow;        // sentinel row = zeros
        u[q] = ld_nt_u4(xl + (size_t)c*F);
      }
      if (more){
        #pragma unroll
        for (int q = 8; q < 16; ++q){
          int c = (q < cnt) ? cb[q] : zrow;
          w[q-8] = ld_nt_u4(xl + (size_t)c*F);
        }
      }
      // accumulate
      #pragma unroll
      for (int q = 0; q < 8; ++q){
        a0 += bf2f((uint16_t)u[q].x); a1 += bf2f((uint16_t)(u[q].x>>16));
        a2 += bf2f((uint16_t)u[q].y); a3 += bf2f((uint16_t)(u[q].y>>16));
        a4 += bf2f((uint16_t)u[q].z); a5 += bf2f((uint16_t)(u[q].z>>16));
        a6 += bf2f((uint16_t)u[q].w); a7 += bf2f((uint16_t)(u[q].w>>16));
      }
      if (more){
        #pragma unroll
        for (int q = 0; q < 8; ++q){
          a0 += bf2f((uint16_t)w[q].x); a1 += bf2f((uint16_t)(w[q].x>>16));
          a2 += bf2f((uint16_t)w[q].y); a3 += bf2f((uint16_t)(w[q].y>>16));
          a4 += bf2f((uint16_t)w[q].z); a5 += bf2f((uint16_t)(w[q].z>>16));
          a6 += bf2f((uint16_t)w[q].w); a7 += bf2f((uint16_t)(w[q].w>>16));
        }
      }
      cv = ncv;
    }
    int r = row0 + i*4 + g;
    float rs = (r < n_dst) ? rs_in[r] : 0.f;
    uint4 pk;
    pk.x = ((uint32_t)f2bf(a1*rs)<<16) | f2bf(a0*rs);
    pk.y = ((uint32_t)f2bf(a3*rs)<<16) | f2bf(a2*rs);
    pk.z = ((uint32_t)f2bf(a5*rs)<<16) | f2bf(a4*rs);
    pk.w = ((uint32_t)f2bf(a7*rs)<<16) | f2bf(a6*rs);
    *(uint4*)&m_lds[(wv*16 + i*4 + g)*FP + l*8] = pk;
  }
  // no barrier: m_lds rows are wave-private, same-wave ds ordering is implicit

  // ---- GEMM (operand-swapped): A = W^T tile, B = aggregated rows ----
  f32x4 acc[8];
  #pragma unroll
  for (int t = 0; t < 8; ++t) acc[t] = (f32x4){0.f,0.f,0.f,0.f};
  const int mrow = lane & 15;
  const int kgrp = lane >> 4;
  #pragma unroll
  for (int k0 = 0; k0 < F; k0 += 32){
    bf16x8 bfrag = *(const bf16x8*)&m_lds[(wv*16 + mrow)*FP + k0 + kgrp*8];
    #pragma unroll
    for (int t = 0; t < 8; ++t){
      bf16x8 afrag = *(const bf16x8*)&Wt[(t*16 + mrow)*FP + k0 + kgrp*8];
      acc[t] = __builtin_amdgcn_mfma_f32_16x16x32_bf16(afrag, bfrag, acc[t], 0, 0, 0);
    }
  }

  // ---- epilogue: lane owns dst-row rr, cols t*16 + quad*4 + (0..3) ----
  const int q4 = kgrp * 4;
  const int rr = row0 + mrow;
  if (rr < n_dst){
    float rsn = (OUT_MODE == 0) ? rs_next[rr] : 1.f;
    #pragma unroll
    for (int t = 0; t < 8; ++t){
      float4 b4 = *(const float4*)&bias[t*16 + q4];
      float v0 = fmaxf(acc[t][0] + b4.x, 0.f);
      float v1 = fmaxf(acc[t][1] + b4.y, 0.f);
      float v2 = fmaxf(acc[t][2] + b4.z, 0.f);
      float v3 = fmaxf(acc[t][3] + b4.w, 0.f);
      if (OUT_MODE == 0){
        uint2 pk;
        pk.x = ((uint32_t)f2bf(v1*rsn)<<16) | f2bf(v0*rsn);
        pk.y = ((uint32_t)f2bf(v3*rsn)<<16) | f2bf(v2*rsn);
        *(uint2*)((uint16_t*)outp + (size_t)rr*F + t*16 + q4) = pk;
      } else {
        float4 o; o.x = v0; o.y = v1; o.z = v2; o.w = v3;
        *(float4*)((float*)outp + (size_t)rr*F + t*16 + q4) = o;
      }
    }
  }
}

extern "C" void kernel_launch(void* const* d_in, const int* in_sizes, int n_in,
                              void* d_out, int out_size, void* d_ws, size_t ws_size,
                              hipStream_t stream) {
  const float* h_p   = (const float*)d_in[0];
  const float* h_d   = (const float*)d_in[1];
  const int* pd_src  = (const int*)d_in[2];
  const int* pd_dst  = (const int*)d_in[3];
  const int* dp_src  = (const int*)d_in[4];
  const int* dp_dst  = (const int*)d_in[5];
  const float* W1_pd = (const float*)d_in[6];   const float* b1_pd = (const float*)d_in[7];
  const float* W1_dp = (const float*)d_in[8];   const float* b1_dp = (const float*)d_in[9];
  const float* W2_pd = (const float*)d_in[10];  const float* b2_pd = (const float*)d_in[11];
  const float* W2_dp = (const float*)d_in[12];  const float* b2_dp = (const float*)d_in[13];
  const float* W3_pd = (const float*)d_in[14];  const float* b3_pd = (const float*)d_in[15];
  const float* W3_dp = (const float*)d_in[16];  const float* b3_dp = (const float*)d_in[17];

  char* w = (char*)d_ws;
  size_t o = 0;
  auto take = [&](size_t bytes)->char*{
    char* p = w + o; o += (bytes + 255) & ~(size_t)255; return p;
  };

  int* cnt_d_in  = (int*)take(4*(size_t)N_D);
  int* cnt_p_in  = (int*)take(4*(size_t)N_P);
  int* off_pd   = (int*)take(4*(size_t)(N_D+1));
  int* off_dp   = (int*)take(4*(size_t)(N_P+1));
  int* bsums    = (int*)take(4*512);
  int* col_pd   = (int*)take(4*(size_t)NE);
  int* col_dp   = (int*)take(4*(size_t)NE);
  float* rs_p_out = (float*)take(4*(size_t)N_P);
  float* rs_p_in  = (float*)take(4*(size_t)N_P);
  float* rs_d_out = (float*)take(4*(size_t)N_D);
  float* rs_d_in  = (float*)take(4*(size_t)N_D);
  uint16_t* wt  = (uint16_t*)take(2*(size_t)6*F*FP);
  // feature buffers have n+1 rows; row n is the zeroed sentinel
  uint16_t* P0  = (uint16_t*)take(2*(size_t)(N_P+1)*F);
  uint16_t* P1  = (uint16_t*)take(2*(size_t)(N_P+1)*F);
  uint16_t* P2  = (uint16_t*)take(2*(size_t)(N_P+1)*F);
  uint16_t* D0  = (uint16_t*)take(2*(size_t)(N_D+1)*F);
  uint16_t* D1  = (uint16_t*)take(2*(size_t)(N_D+1)*F);
  uint16_t* D2  = (uint16_t*)take(2*(size_t)(N_D+1)*F);

  // hist (19.2 MB) aliases P1's first bytes (25.6 MB buffer): hist is dead
  // after scatter; convert's only P1 touch is the sentinel row at byte offset
  // 25.6 MB — past the hist region. Layer-1 gconv (writes P1 body) runs
  // strictly after the build on the same stream.
  int* hist = (int*)P1;

  const float4* hp4 = (const float4*)h_p;
  const float4* hd4 = (const float4*)h_d;
  uint2* P0u = (uint2*)P0;
  uint2* D0u = (uint2*)D0;
  uint16_t* z0 = P0 + (size_t)N_P*F;
  uint16_t* z1 = D0 + (size_t)N_D*F;
  uint16_t* z2 = P1 + (size_t)N_P*F;
  uint16_t* z3 = D1 + (size_t)N_D*F;
  uint16_t* z4 = P2 + (size_t)N_P*F;
  uint16_t* z5 = D2 + (size_t)N_D*F;

  void* kargs[] = {
    (void*)&pd_src, (void*)&pd_dst, (void*)&dp_src, (void*)&dp_dst,
    (void*)&hist, (void*)&cnt_d_in, (void*)&cnt_p_in,
    (void*)&rs_p_out, (void*)&rs_p_in, (void*)&rs_d_out, (void*)&rs_d_in,
    (void*)&bsums, (void*)&off_pd, (void*)&off_dp, (void*)&col_pd, (void*)&col_dp,
    (void*)&hp4, (void*)&hd4, (void*)&P0u, (void*)&D0u,
    (void*)&W1_pd, (void*)&W1_dp, (void*)&W2_pd, (void*)&W2_dp, (void*)&W3_pd, (void*)&W3_dp,
    (void*)&wt,
    (void*)&z0, (void*)&z1, (void*)&z2, (void*)&z3, (void*)&z4, (void*)&z5
  };
  hipError_t cerr = hipLaunchCooperativeKernel(reinterpret_cast<void*>(k_build),
                                               dim3(NBLD), dim3(512), kargs, 0, stream);
  if (cerr != hipSuccess){
    // fallback: proven R4 discrete chain (coop launch unsupported/failed)
    const int nbA = NBA, nbB = NBB;
    k_hist<<<4*HPH*NCHK, 512, 0, stream>>>(pd_src, pd_dst, dp_src, dp_dst, hist);
    k_sumdeg<<<dim3((N_P+255)/256, 4), 256, 0, stream>>>(
        hist, cnt_d_in, cnt_p_in, rs_p_out, rs_p_in, rs_d_out, rs_d_in);
    k_scan1<<<nbA+nbB, 512, 0, stream>>>(cnt_d_in, N_D, cnt_p_in, N_P, bsums, nbA);
    k_scan2<<<2, 256, 0, stream>>>(bsums, nbA, nbB);
    k_scan3<<<nbA+nbB, 512, 0, stream>>>(cnt_d_in, N_D, cnt_p_in, N_P, bsums, nbA, off_pd, off_dp);
    k_scatter<<<2*HPS*NCHK, 512, 0, stream>>>(pd_src, pd_dst, dp_src, dp_dst,
                                              off_pd, off_dp, hist, col_pd, col_dp);
    k_convert<<<CVT_TOT, 256, 0, stream>>>(
        hp4, hd4, rs_p_out, rs_d_out, P0u, D0u,
        W1_pd, W1_dp, W2_pd, W2_dp, W3_pd, W3_dp, wt,
        z0, z1, z2, z3, z4, z5);
  }

  const int gd = (N_D + 63)/64, gp = (N_P + 63)/64;
  // layer 1 (both directions fused in one dispatch)
  k_gconv2<0><<<gd+gp, 256, 0, stream>>>(
      P0, off_pd, col_pd, rs_d_in, wt + 0*F*FP, b1_pd, rs_d_out, D1, N_D, N_P, gd,
      D0, off_dp, col_dp, rs_p_in, wt + 1*F*FP, b1_dp, rs_p_out, P1, N_P, N_D);
  // layer 2
  k_gconv2<0><<<gd+gp, 256, 0, stream>>>(
      P1, off_pd, col_pd, rs_d_in, wt + 2*F*FP, b2_pd, rs_d_out, D2, N_D, N_P, gd,
      D1, off_dp, col_dp, rs_p_in, wt + 3*F*FP, b2_dp, rs_p_out, P2, N_P, N_D);
  // layer 3 (fp32 outputs: h_p3 first, then h_d3)
  k_gconv2<1><<<gd+gp, 256, 0, stream>>>(
      P2, off_pd, col_pd, rs_d_in, wt + 4*F*FP, b3_pd, nullptr, (float*)d_out + (size_t)N_P*F, N_D, N_P, gd,
      D2, off_dp, col_dp, rs_p_in, wt + 5*F*FP, b3_dp, nullptr, (float*)d_out, N_P, N_D);
}

// Round 7
// 504.753 us; speedup vs baseline: 1.4722x; 1.4722x over previous
//
#include <hip/hip_runtime.h>
#include <stdint.h>

#define N_P 100000
#define N_D 50000
#define NE  600000
#define F   128
#define FP  136   // padded LDS/global row stride (272B = 17*16B: 16B-aligned, 2-way-free banks)

// counting-sort build params (R7: u16 global hist, NCHK=32, HPH=4)
#define NCHK   32
#define CHKE   18752                 // edges per chunk (mult of 4); last chunk = 18688
#define HPH    4                     // hist partitions (u16-packed LDS -> 50 KB)
#define HPS    8                     // scatter partitions (int cursors -> 50 KB LDS)
// hist layout (u16 elements): A0 pd_src[32][N_P] | A1 pd_dst[32][N_D] | A2 dp_src[32][N_D] | A3 dp_dst[32][N_P]
#define HOFS_A0 ((size_t)0)
#define HOFS_A1 ((size_t)NCHK*N_P)
#define HOFS_A2 ((size_t)NCHK*N_P + (size_t)NCHK*N_D)
#define HOFS_A3 ((size_t)NCHK*N_P + (size_t)2*NCHK*N_D)
// convert work units ("blocks" of 256 threads)
#define CVT_TOT (6 + (N_P+N_D)*F/4/256)   // 6 + 18750 = 18756

typedef __attribute__((ext_vector_type(8))) __bf16 bf16x8;
typedef __attribute__((ext_vector_type(4))) float  f32x4;
typedef unsigned int __attribute__((ext_vector_type(4))) u32x4;

static __device__ __forceinline__ float bf2f(uint16_t u){
  union{float f;uint32_t i;} v; v.i = ((uint32_t)u)<<16; return v.f;
}
static __device__ __forceinline__ uint16_t f2bf(float f){
  union{float f;uint32_t i;} v; v.f = f;
  uint32_t i = v.i;
  uint32_t r = i + 0x7fffu + ((i>>16)&1u);   // round-to-nearest-even
  return (uint16_t)(r>>16);
}
// non-temporal 16B load (evict-first: gather rows have no L1 reuse)
static __device__ __forceinline__ uint4 ld_nt_u4(const uint16_t* p){
  u32x4 v = __builtin_nontemporal_load((const u32x4*)p);
  uint4 r; r.x = v.x; r.y = v.y; r.z = v.z; r.w = v.w; return r;
}

// ---------------- phase 1: per-(array, part, chunk) LDS histogram -----------
// grid = 4*HPH*NCHK = 512 blocks x 512 thr (2 blk/CU TLP). u16-packed counts
// in LDS AND in global (per-chunk count < 2^16): hist stays 19.2 MB at
// NCHK=32. LDS atomics (R3 lesson: global atomics are 100us-class).
__global__ __launch_bounds__(512) void k_hist(
    const int* __restrict__ pd_src, const int* __restrict__ pd_dst,
    const int* __restrict__ dp_src, const int* __restrict__ dp_dst,
    uint16_t* __restrict__ hist){
  __shared__ uint32_t cnt[(N_P/HPH)/2];   // 12500 words = 50 KB
  const int b = blockIdx.x;
  const int arr = b >> 7, part = (b >> 5) & 3, chunk = b & 31;
  const int* src; int N; size_t hofs;
  switch(arr){
    case 0:  src = pd_src; N = N_P; hofs = HOFS_A0; break;
    case 1:  src = pd_dst; N = N_D; hofs = HOFS_A1; break;
    case 2:  src = dp_src; N = N_D; hofs = HOFS_A2; break;
    default: src = dp_dst; N = N_P; hofs = HOFS_A3; break;
  }
  const int PART = N / HPH;
  const int nw   = PART >> 1;
  const int lo   = part * PART;
  for (int i = threadIdx.x; i < nw; i += 512) cnt[i] = 0;
  __syncthreads();
  const int e0 = chunk*CHKE, e1 = min(e0 + CHKE, NE);
  const uint4* s4 = (const uint4*)(src + e0);
  const int n4 = (e1 - e0) >> 2;
  for (int i = threadIdx.x; i < n4; i += 512){
    uint4 v = s4[i];
    int a0 = (int)v.x - lo, a1 = (int)v.y - lo, a2 = (int)v.z - lo, a3 = (int)v.w - lo;
    if ((unsigned)a0 < (unsigned)PART) atomicAdd(&cnt[a0>>1], 1u << ((a0&1)<<4));
    if ((unsigned)a1 < (unsigned)PART) atomicAdd(&cnt[a1>>1], 1u << ((a1&1)<<4));
    if ((unsigned)a2 < (unsigned)PART) atomicAdd(&cnt[a2>>1], 1u << ((a2&1)<<4));
    if ((unsigned)a3 < (unsigned)PART) atomicAdd(&cnt[a3>>1], 1u << ((a3&1)<<4));
  }
  __syncthreads();
  // LDS word already packs nodes (2i, 2i+1) as u16 pair == global u16 layout
  uint32_t* out32 = (uint32_t*)(hist + hofs + (size_t)chunk*N + lo);
  for (int i = threadIdx.x; i < nw; i += 512) out32[i] = cnt[i];
}

// ---------------- phase 2: chunk-prefix (dst arrays) + degrees + rsqrt ------
// one thread per NODE PAIR (u32 = two packed u16 counts per chunk).
__global__ __launch_bounds__(512) void k_sumdeg(
    uint16_t* __restrict__ hist,
    int* __restrict__ cnt_d_in, int* __restrict__ cnt_p_in,
    float* __restrict__ rs_p_out, float* __restrict__ rs_p_in,
    float* __restrict__ rs_d_out, float* __restrict__ rs_d_in){
  const int gid = blockIdx.x*512 + threadIdx.x;
  if (gid >= (N_P + N_D)) return;          // 150000 pairs total
  int arr, pidx;
  if      (gid < N_P/2)        { arr = 0; pidx = gid; }
  else if (gid < N_P/2+N_D/2)  { arr = 1; pidx = gid - N_P/2; }
  else if (gid < N_P/2+N_D)    { arr = 2; pidx = gid - N_P/2 - N_D/2; }
  else                         { arr = 3; pidx = gid - N_P/2 - N_D; }
  int N; size_t hofs; bool pre;
  switch(arr){
    case 0:  N = N_P; hofs = HOFS_A0; pre = false; break;
    case 1:  N = N_D; hofs = HOFS_A1; pre = true;  break;
    case 2:  N = N_D; hofs = HOFS_A2; pre = false; break;
    default: N = N_P; hofs = HOFS_A3; pre = true;  break;
  }
  uint32_t* h32 = (uint32_t*)(hist + hofs) + pidx;
  const int stride = N >> 1;
  int run0 = 0, run1 = 0;
  if (pre){
    #pragma unroll 4
    for (int c = 0; c < NCHK; ++c){
      uint32_t w = h32[(size_t)c*stride];
      h32[(size_t)c*stride] = (uint32_t)run0 | ((uint32_t)run1 << 16);
      run0 += (int)(w & 0xffffu); run1 += (int)(w >> 16);
    }
  } else {
    #pragma unroll 4
    for (int c = 0; c < NCHK; ++c){
      uint32_t w = h32[(size_t)c*stride];
      run0 += (int)(w & 0xffffu); run1 += (int)(w >> 16);
    }
  }
  const int idx = 2*pidx;
  float rs0 = rsqrtf((float)max(run0, 1));
  float rs1 = rsqrtf((float)max(run1, 1));
  switch(arr){
    case 0:  rs_p_out[idx] = rs0; rs_p_out[idx+1] = rs1; break;
    case 1:  cnt_d_in[idx] = run0; cnt_d_in[idx+1] = run1;
             rs_d_in[idx] = rs0;  rs_d_in[idx+1] = rs1;  break;
    case 2:  rs_d_out[idx] = rs0; rs_d_out[idx+1] = rs1; break;
    default: cnt_p_in[idx] = run0; cnt_p_in[idx+1] = run1;
             rs_p_in[idx] = rs0;  rs_p_in[idx+1] = rs1;  break;
  }
}

// ---------------- hierarchical exclusive scan -------------------------------
__global__ void k_scan1(const int* __restrict__ cA, int nA,
                        const int* __restrict__ cB, int nB,
                        int* __restrict__ bsums, int nbA){
  __shared__ int red[8];
  int b = blockIdx.x, t = threadIdx.x;
  const int* in; int n, bi, slot;
  if (b < nbA){ in = cA; n = nA; bi = b;       slot = bi; }
  else        { in = cB; n = nB; bi = b - nbA; slot = 256 + bi; }
  int i = bi*512 + t;
  int v = (i < n) ? in[i] : 0;
  #pragma unroll
  for (int o = 32; o; o >>= 1) v += __shfl_down(v, o, 64);
  if ((t & 63) == 0) red[t >> 6] = v;
  __syncthreads();
  if (t == 0){ int s = 0; for (int k = 0; k < 8; ++k) s += red[k]; bsums[slot] = s; }
}

__global__ void k_scan2(int* bsums, int nbA, int nbB){
  __shared__ int sh[256];
  int seg = blockIdx.x, t = threadIdx.x;
  int nb = seg ? nbB : nbA;
  int* p = bsums + seg*256;
  int v = (t < nb) ? p[t] : 0;
  sh[t] = v; __syncthreads();
  for (int ofs = 1; ofs < 256; ofs <<= 1){
    int u = (t >= ofs) ? sh[t-ofs] : 0; __syncthreads();
    sh[t] += u; __syncthreads();
  }
  if (t < nb) p[t] = sh[t] - v;   // exclusive
}

__global__ void k_scan3(const int* __restrict__ cA, int nA,
                        const int* __restrict__ cB, int nB,
                        const int* __restrict__ bsums, int nbA,
                        int* __restrict__ offA, int* __restrict__ offB){
  __shared__ int sh[512];
  int b = blockIdx.x, t = threadIdx.x;
  const int* in; int n, bi; int* out; int base;
  if (b < nbA){ in = cA; n = nA; bi = b;       out = offA; base = bsums[bi]; }
  else        { in = cB; n = nB; bi = b - nbA; out = offB; base = bsums[256+bi]; }
  int i = bi*512 + t;
  int v = (i < n) ? in[i] : 0;
  sh[t] = v; __syncthreads();
  for (int ofs = 1; ofs < 512; ofs <<= 1){
    int u = (t >= ofs) ? sh[t-ofs] : 0; __syncthreads();
    sh[t] += u; __syncthreads();
  }
  if (i < n) out[i] = base + sh[t] - v;
  if (b == 0 && t == 0){ offA[nA] = NE; offB[nB] = NE; }
}

// ---------------- phase 3: scatter ------------------------------------------
// grid = 2*HPS*NCHK = 512 blocks x 512 thr. base[] doubles as the rank
// counter (LDS atomicAdd returns the write position). hist layout is
// [chunk][global node] so scatter's HPS=8 composes with hist's HPH=4.
__global__ __launch_bounds__(512) void k_scatter(
    const int* __restrict__ pd_src, const int* __restrict__ pd_dst,
    const int* __restrict__ dp_src, const int* __restrict__ dp_dst,
    const int* __restrict__ off_pd, const int* __restrict__ off_dp,
    const uint16_t* __restrict__ hist,
    int* __restrict__ col_pd, int* __restrict__ col_dp){
  __shared__ int base[N_P/HPS];   // 12500 ints = 50 KB
  const int b = blockIdx.x;
  const int gph = b >> 8, part = (b >> 5) & 7, chunk = b & 31;
  const int* dsts; const int* srcs; const int* off; int* col; int N; size_t hofs;
  if (gph == 0){ dsts = pd_dst; srcs = pd_src; off = off_pd; col = col_pd; N = N_D; hofs = HOFS_A1; }
  else         { dsts = dp_dst; srcs = dp_src; off = off_dp; col = col_dp; N = N_P; hofs = HOFS_A3; }
  const int PART = N / HPS;
  const int lo = part * PART;
  const uint32_t* hc32 = (const uint32_t*)(hist + hofs + (size_t)chunk*N + lo);
  const int* offp = off + lo;
  for (int i = threadIdx.x; i < (PART>>1); i += 512){
    uint32_t w = hc32[i];
    base[2*i]   = offp[2*i]   + (int)(w & 0xffffu);
    base[2*i+1] = offp[2*i+1] + (int)(w >> 16);
  }
  __syncthreads();
  const int e0 = chunk*CHKE, e1 = min(e0 + CHKE, NE);
  const uint4* d4 = (const uint4*)(dsts + e0);
  const int n4 = (e1 - e0) >> 2;
  for (int i = threadIdx.x; i < n4; i += 512){
    uint4 d = d4[i];
    int a0 = (int)d.x - lo, a1 = (int)d.y - lo, a2 = (int)d.z - lo, a3 = (int)d.w - lo;
    int e = e0 + 4*i;
    if ((unsigned)a0 < (unsigned)PART){ int p = atomicAdd(&base[a0], 1); col[p] = srcs[e+0]; }
    if ((unsigned)a1 < (unsigned)PART){ int p = atomicAdd(&base[a1], 1); col[p] = srcs[e+1]; }
    if ((unsigned)a2 < (unsigned)PART){ int p = atomicAdd(&base[a2], 1); col[p] = srcs[e+2]; }
    if ((unsigned)a3 < (unsigned)PART){ int p = atomicAdd(&base[a3], 1); col[p] = srcs[e+3]; }
  }
}

// ------ merged: W prep (blocks 0..5) + fp32->prescaled bf16 convert ---------
__global__ void k_convert(const float4* __restrict__ hp, const float4* __restrict__ hd,
                          const float* __restrict__ rs_po, const float* __restrict__ rs_do,
                          uint2* __restrict__ P0, uint2* __restrict__ D0,
                          const float* w0,const float* w1,const float* w2,
                          const float* w3,const float* w4,const float* w5,
                          uint16_t* __restrict__ wt,
                          uint16_t* z0, uint16_t* z1, uint16_t* z2,
                          uint16_t* z3, uint16_t* z4, uint16_t* z5){
  if (blockIdx.x < 6){
    int m = blockIdx.x;
    const float* W; uint16_t* Z;
    switch(m){ case 0:W=w0;Z=z0;break; case 1:W=w1;Z=z1;break; case 2:W=w2;Z=z2;break;
               case 3:W=w3;Z=z3;break; case 4:W=w4;Z=z4;break; default:W=w5;Z=z5; }
    uint16_t* T = wt + m*F*FP;
    for (int idx = threadIdx.x; idx < F*F; idx += 256){
      int k = idx >> 7, j = idx & 127;
      T[j*FP + k] = f2bf(W[idx]);
    }
    if (threadIdx.x < F) Z[threadIdx.x] = 0;   // sentinel zero row
    return;
  }
  int i = (blockIdx.x - 6)*256 + threadIdx.x;
  const int nP4 = N_P*F/4, nD4 = N_D*F/4;
  if (i < nP4){
    float4 v = hp[i]; float s = rs_po[i >> 5];
    uint2 r;
    r.x = ((uint32_t)f2bf(v.y*s)<<16) | f2bf(v.x*s);
    r.y = ((uint32_t)f2bf(v.w*s)<<16) | f2bf(v.z*s);
    P0[i] = r;
  } else {
    int j = i - nP4;
    if (j < nD4){
      float4 v = hd[j]; float s = rs_do[j >> 5];
      uint2 r;
      r.x = ((uint32_t)f2bf(v.y*s)<<16) | f2bf(v.x*s);
      r.y = ((uint32_t)f2bf(v.w*s)<<16) | f2bf(v.z*s);
      D0[j] = r;
    }
  }
}

// ---------------- fused gconv PAIR (R1 gather structure, proven) ------------
// Gather: wave = 4 groups of 16 lanes; group g owns a row, lane l holds
// features [8l,8l+8). Broadcast all 16 col indices up front, issue ALL 8
// (16 when deg>8) uint4 NT gather loads into register arrays, THEN
// accumulate. (256,4) bounds; R2's dual-stream regressed — do not re-add.
// R7 epilogue (OUT_MODE 0): WRITE_SIZE was 2x logical (8B/lane stores cover
// only 32B per 64B line -> write-allocate RMW). Now stage scaled bf16 C into
// the (free, wave-private) m_lds rows, then store 1KB fully-coalesced per
// wave (block rows are consecutive in global). No barrier: same-wave DS
// ordering is implicit.
template<int OUT_MODE>
__global__ __launch_bounds__(256, 4) void k_gconv2(
    const uint16_t* __restrict__ xA, const int* __restrict__ offAp, const int* __restrict__ colA,
    const float* __restrict__ rsA, const uint16_t* __restrict__ WtA, const float* __restrict__ biasA,
    const float* __restrict__ rsnA, void* __restrict__ outA, int ndA, int nsA, int nblkA,
    const uint16_t* __restrict__ xB, const int* __restrict__ offBp, const int* __restrict__ colB,
    const float* __restrict__ rsB, const uint16_t* __restrict__ WtB, const float* __restrict__ biasB,
    const float* __restrict__ rsnB, void* __restrict__ outB, int ndB, int nsB)
{
  __shared__ uint16_t m_lds[64*FP];    // 17408 B
  const int tid  = threadIdx.x;
  const int lane = tid & 63;
  const int wv   = tid >> 6;

  const uint16_t* x; const int* off; const int* col; const float* rs_in;
  const uint16_t* Wt; const float* bias; const float* rs_next; void* outp;
  int n_dst, zrow, bid;
  if ((int)blockIdx.x < nblkA){
    x = xA; off = offAp; col = colA; rs_in = rsA; Wt = WtA; bias = biasA;
    rs_next = rsnA; outp = outA; n_dst = ndA; zrow = nsA; bid = blockIdx.x;
  } else {
    x = xB; off = offBp; col = colB; rs_in = rsB; Wt = WtB; bias = biasB;
    rs_next = rsnB; outp = outB; n_dst = ndB; zrow = nsB; bid = blockIdx.x - nblkA;
  }

  // ---- aggregation ----
  const int row0 = bid*64 + wv*16;
  const int g    = lane >> 4;     // group
  const int l    = lane & 15;     // lane in group; features [8l, 8l+8)
  const uint16_t* xl = x + l*8;   // lane-fixed feature slice base

  int e0a[4], e1a[4], cva[4];
  #pragma unroll
  for (int i = 0; i < 4; ++i){
    int r = row0 + i*4 + g;
    bool rv = r < n_dst;
    e0a[i] = rv ? off[r]   : 0;
    e1a[i] = rv ? off[r+1] : 0;
  }
  #pragma unroll
  for (int i = 0; i < 4; ++i){
    int last = (e1a[i] > 0) ? e1a[i]-1 : 0;
    int idx  = e0a[i] + l;
    cva[i] = col[idx < e1a[i] ? idx : last];   // hoisted first batch (4 loads in flight)
  }

  #pragma unroll
  for (int i = 0; i < 4; ++i){
    int e0 = e0a[i], e1 = e1a[i];
    int cv = cva[i];
    float a0=0.f,a1=0.f,a2=0.f,a3=0.f,a4=0.f,a5=0.f,a6=0.f,a7=0.f;
    for (int e = e0; e < e1; e += 16){
      // prefetch next batch of col indices (clamped; harmless L1 re-read)
      int nidx = e + 16 + l;
      int ncv  = col[nidx < e1 ? nidx : e1-1];
      int cnt  = e1 - e;
      const bool more = (cnt > 8);
      // broadcast col indices for the whole batch up front (VALU/LDS only)
      int cb[16];
      #pragma unroll
      for (int q = 0; q < 8; ++q) cb[q] = __shfl(cv, g*16 + q, 64);
      if (more){
        #pragma unroll
        for (int q = 8; q < 16; ++q) cb[q] = __shfl(cv, g*16 + q, 64);
      }
      // issue ALL gather loads before any accumulation (max MLP)
      uint4 u[8], w[8];
      #pragma unroll
      for (int q = 0; q < 8; ++q){
        int c = (q < cnt) ? cb[q] : zrow;        // sentinel row = zeros
        u[q] = ld_nt_u4(xl + (size_t)c*F);
      }
      if (more){
        #pragma unroll
        for (int q = 8; q < 16; ++q){
          int c = (q < cnt) ? cb[q] : zrow;
          w[q-8] = ld_nt_u4(xl + (size_t)c*F);
        }
      }
      // accumulate
      #pragma unroll
      for (int q = 0; q < 8; ++q){
        a0 += bf2f((uint16_t)u[q].x); a1 += bf2f((uint16_t)(u[q].x>>16));
        a2 += bf2f((uint16_t)u[q].y); a3 += bf2f((uint16_t)(u[q].y>>16));
        a4 += bf2f((uint16_t)u[q].z); a5 += bf2f((uint16_t)(u[q].z>>16));
        a6 += bf2f((uint16_t)u[q].w); a7 += bf2f((uint16_t)(u[q].w>>16));
      }
      if (more){
        #pragma unroll
        for (int q = 0; q < 8; ++q){
          a0 += bf2f((uint16_t)w[q].x); a1 += bf2f((uint16_t)(w[q].x>>16));
          a2 += bf2f((uint16_t)w[q].y); a3 += bf2f((uint16_t)(w[q].y>>16));
          a4 += bf2f((uint16_t)w[q].z); a5 += bf2f((uint16_t)(w[q].z>>16));
          a6 += bf2f((uint16_t)w[q].w); a7 += bf2f((uint16_t)(w[q].w>>16));
        }
      }
      cv = ncv;
    }
    int r = row0 + i*4 + g;
    float rs = (r < n_dst) ? rs_in[r] : 0.f;
    uint4 pk;
    pk.x = ((uint32_t)f2bf(a1*rs)<<16) | f2bf(a0*rs);
    pk.y = ((uint32_t)f2bf(a3*rs)<<16) | f2bf(a2*rs);
    pk.z = ((uint32_t)f2bf(a5*rs)<<16) | f2bf(a4*rs);
    pk.w = ((uint32_t)f2bf(a7*rs)<<16) | f2bf(a6*rs);
    *(uint4*)&m_lds[(wv*16 + i*4 + g)*FP + l*8] = pk;
  }
  // no barrier: m_lds rows are wave-private, same-wave ds ordering is implicit

  // ---- GEMM (operand-swapped): A = W^T tile, B = aggregated rows ----
  f32x4 acc[8];
  #pragma unroll
  for (int t = 0; t < 8; ++t) acc[t] = (f32x4){0.f,0.f,0.f,0.f};
  const int mrow = lane & 15;
  const int kgrp = lane >> 4;
  #pragma unroll
  for (int k0 = 0; k0 < F; k0 += 32){
    bf16x8 bfrag = *(const bf16x8*)&m_lds[(wv*16 + mrow)*FP + k0 + kgrp*8];
    #pragma unroll
    for (int t = 0; t < 8; ++t){
      bf16x8 afrag = *(const bf16x8*)&Wt[(t*16 + mrow)*FP + k0 + kgrp*8];
      acc[t] = __builtin_amdgcn_mfma_f32_16x16x32_bf16(afrag, bfrag, acc[t], 0, 0, 0);
    }
  }

  // ---- epilogue ----
  const int q4 = kgrp * 4;
  const int rr = row0 + mrow;
  if (OUT_MODE == 0){
    // stage scaled bf16 C into m_lds (GEMM reads are done; wave-private rows;
    // in-order per-wave DS pipeline makes read-before-overwrite safe)
    float rsn = (rr < n_dst) ? rs_next[rr] : 0.f;
    #pragma unroll
    for (int t = 0; t < 8; ++t){
      float4 b4 = *(const float4*)&bias[t*16 + q4];
      float v0 = fmaxf(acc[t][0] + b4.x, 0.f) * rsn;
      float v1 = fmaxf(acc[t][1] + b4.y, 0.f) * rsn;
      float v2 = fmaxf(acc[t][2] + b4.z, 0.f) * rsn;
      float v3 = fmaxf(acc[t][3] + b4.w, 0.f) * rsn;
      uint2 pk;
      pk.x = ((uint32_t)f2bf(v1)<<16) | f2bf(v0);
      pk.y = ((uint32_t)f2bf(v3)<<16) | f2bf(v2);
      *(uint2*)&m_lds[(wv*16 + mrow)*FP + t*16 + q4] = pk;
    }
    // coalesced store: wave covers rows row0..row0+15 (contiguous 4 KB in
    // global). Per it: lane writes 16B at region byte offset it*1024+lane*16
    // -> 1 KB fully-coalesced per instruction, full 64B lines.
    uint16_t* outg = (uint16_t*)outp;
    const int lr = lane & 15;   // col chunk: bytes lr*16 within the row
    const int lw = lane >> 4;   // row subgroup
    #pragma unroll
    for (int it = 0; it < 4; ++it){
      int rowi = row0 + it*4 + lw;
      if (rowi < n_dst){
        uint4 vv = *(const uint4*)&m_lds[(wv*16 + it*4 + lw)*FP + lr*8];
        *(uint4*)&outg[(size_t)rowi*F + lr*8] = vv;
      }
    }
  } else {
    // fp32 out: per (t), each row receives 64B contiguous (4 lanes x 16B)
    // -> full lines already; keep direct stores.
    if (rr < n_dst){
      #pragma unroll
      for (int t = 0; t < 8; ++t){
        float4 b4 = *(const float4*)&bias[t*16 + q4];
        float4 o;
        o.x = fmaxf(acc[t][0] + b4.x, 0.f);
        o.y = fmaxf(acc[t][1] + b4.y, 0.f);
        o.z = fmaxf(acc[t][2] + b4.z, 0.f);
        o.w = fmaxf(acc[t][3] + b4.w, 0.f);
        *(float4*)((float*)outp + (size_t)rr*F + t*16 + q4) = o;
      }
    }
  }
}

extern "C" void kernel_launch(void* const* d_in, const int* in_sizes, int n_in,
                              void* d_out, int out_size, void* d_ws, size_t ws_size,
                              hipStream_t stream) {
  const float* h_p   = (const float*)d_in[0];
  const float* h_d   = (const float*)d_in[1];
  const int* pd_src  = (const int*)d_in[2];
  const int* pd_dst  = (const int*)d_in[3];
  const int* dp_src  = (const int*)d_in[4];
  const int* dp_dst  = (const int*)d_in[5];
  const float* W1_pd = (const float*)d_in[6];   const float* b1_pd = (const float*)d_in[7];
  const float* W1_dp = (const float*)d_in[8];   const float* b1_dp = (const float*)d_in[9];
  const float* W2_pd = (const float*)d_in[10];  const float* b2_pd = (const float*)d_in[11];
  const float* W2_dp = (const float*)d_in[12];  const float* b2_dp = (const float*)d_in[13];
  const float* W3_pd = (const float*)d_in[14];  const float* b3_pd = (const float*)d_in[15];
  const float* W3_dp = (const float*)d_in[16];  const float* b3_dp = (const float*)d_in[17];

  char* w = (char*)d_ws;
  size_t o = 0;
  auto take = [&](size_t bytes)->char*{
    char* p = w + o; o += (bytes + 255) & ~(size_t)255; return p;
  };

  int* cnt_d_in  = (int*)take(4*(size_t)N_D);
  int* cnt_p_in  = (int*)take(4*(size_t)N_P);
  int* off_pd   = (int*)take(4*(size_t)(N_D+1));
  int* off_dp   = (int*)take(4*(size_t)(N_P+1));
  int* bsums    = (int*)take(4*512);
  int* col_pd   = (int*)take(4*(size_t)NE);
  int* col_dp   = (int*)take(4*(size_t)NE);
  float* rs_p_out = (float*)take(4*(size_t)N_P);
  float* rs_p_in  = (float*)take(4*(size_t)N_P);
  float* rs_d_out = (float*)take(4*(size_t)N_D);
  float* rs_d_in  = (float*)take(4*(size_t)N_D);
  uint16_t* wt  = (uint16_t*)take(2*(size_t)6*F*FP);
  // feature buffers have n+1 rows; row n is the zeroed sentinel
  uint16_t* P0  = (uint16_t*)take(2*(size_t)(N_P+1)*F);
  uint16_t* P1  = (uint16_t*)take(2*(size_t)(N_P+1)*F);
  uint16_t* P2  = (uint16_t*)take(2*(size_t)(N_P+1)*F);
  uint16_t* D0  = (uint16_t*)take(2*(size_t)(N_D+1)*F);
  uint16_t* D1  = (uint16_t*)take(2*(size_t)(N_D+1)*F);
  uint16_t* D2  = (uint16_t*)take(2*(size_t)(N_D+1)*F);

  // hist (u16, 19.2 MB) aliases P1 (25.6 MB): dead until k_convert/gconv,
  // which run strictly after k_scatter on the same stream.
  uint16_t* hist = P1;

  k_hist<<<4*HPH*NCHK, 512, 0, stream>>>(pd_src, pd_dst, dp_src, dp_dst, hist);
  k_sumdeg<<<((N_P+N_D) + 511)/512, 512, 0, stream>>>(
      hist, cnt_d_in, cnt_p_in, rs_p_out, rs_p_in, rs_d_out, rs_d_in);
  const int nbA = (N_D + 511)/512;   // 98
  const int nbB = (N_P + 511)/512;   // 196
  k_scan1<<<nbA+nbB, 512, 0, stream>>>(cnt_d_in, N_D, cnt_p_in, N_P, bsums, nbA);
  k_scan2<<<2, 256, 0, stream>>>(bsums, nbA, nbB);
  k_scan3<<<nbA+nbB, 512, 0, stream>>>(cnt_d_in, N_D, cnt_p_in, N_P, bsums, nbA, off_pd, off_dp);
  k_scatter<<<2*HPS*NCHK, 512, 0, stream>>>(pd_src, pd_dst, dp_src, dp_dst,
                                            off_pd, off_dp, hist, col_pd, col_dp);
  k_convert<<<CVT_TOT, 256, 0, stream>>>(
      (const float4*)h_p, (const float4*)h_d, rs_p_out, rs_d_out, (uint2*)P0, (uint2*)D0,
      W1_pd, W1_dp, W2_pd, W2_dp, W3_pd, W3_dp, wt,
      P0 + (size_t)N_P*F, D0 + (size_t)N_D*F,
      P1 + (size_t)N_P*F, D1 + (size_t)N_D*F,
      P2 + (size_t)N_P*F, D2 + (size_t)N_D*F);

  const int gd = (N_D + 63)/64, gp = (N_P + 63)/64;
  // layer 1 (both directions fused in one dispatch)
  k_gconv2<0><<<gd+gp, 256, 0, stream>>>(
      P0, off_pd, col_pd, rs_d_in, wt + 0*F*FP, b1_pd, rs_d_out, D1, N_D, N_P, gd,
      D0, off_dp, col_dp, rs_p_in, wt + 1*F*FP, b1_dp, rs_p_out, P1, N_P, N_D);
  // layer 2
  k_gconv2<0><<<gd+gp, 256, 0, stream>>>(
      P1, off_pd, col_pd, rs_d_in, wt + 2*F*FP, b2_pd, rs_d_out, D2, N_D, N_P, gd,
      D1, off_dp, col_dp, rs_p_in, wt + 3*F*FP, b2_dp, rs_p_out, P2, N_P, N_D);
  // layer 3 (fp32 outputs: h_p3 first, then h_d3)
  k_gconv2<1><<<gd+gp, 256, 0, stream>>>(
      P2, off_pd, col_pd, rs_d_in, wt + 4*F*FP, b3_pd, nullptr, (float*)d_out + (size_t)N_P*F, N_D, N_P, gd,
      D2, off_dp, col_dp, rs_p_in, wt + 5*F*FP, b3_dp, nullptr, (float*)d_out, N_P, N_D);
}

// Round 8
// 433.945 us; speedup vs baseline: 1.7124x; 1.1632x over previous
//
#include <hip/hip_runtime.h>
#include <stdint.h>

#define N_P 100000
#define N_D 50000
#define NE  600000
#define F   128
#define FP  136   // padded LDS/global row stride (272B = 17*16B: 16B-aligned, 2-way-free banks)

// counting-sort build params (u16 global hist, NCHK=32, HPH=4)
#define NCHK   32
#define CHKE   18752                 // edges per chunk (mult of 4); last chunk = 18688
#define HPH    4                     // hist partitions (u16-packed LDS -> 50 KB)
#define HPS    8                     // scatter partitions (int cursors -> 50 KB LDS)
// hist layout (u16 elements): A0 pd_src[32][N_P] | A1 pd_dst[32][N_D] | A2 dp_src[32][N_D] | A3 dp_dst[32][N_P]
#define HOFS_A0 ((size_t)0)
#define HOFS_A1 ((size_t)NCHK*N_P)
#define HOFS_A2 ((size_t)NCHK*N_P + (size_t)NCHK*N_D)
#define HOFS_A3 ((size_t)NCHK*N_P + (size_t)2*NCHK*N_D)
// convert work units ("blocks" of 256 threads)
#define CVT_TOT (6 + (N_P+N_D)*F/4/256)   // 6 + 18750 = 18756

typedef __attribute__((ext_vector_type(8))) __bf16 bf16x8;
typedef __attribute__((ext_vector_type(4))) float  f32x4;

static __device__ __forceinline__ float bf2f(uint16_t u){
  union{float f;uint32_t i;} v; v.i = ((uint32_t)u)<<16; return v.f;
}
static __device__ __forceinline__ uint16_t f2bf(float f){
  union{float f;uint32_t i;} v; v.f = f;
  uint32_t i = v.i;
  uint32_t r = i + 0x7fffu + ((i>>16)&1u);   // round-to-nearest-even
  return (uint16_t)(r>>16);
}

// ---------------- phase 1: per-(array, part, chunk) LDS histogram -----------
// grid = 4*HPH*NCHK = 512 blocks x 512 thr (2 blk/CU TLP). u16-packed counts
// in LDS AND in global (per-chunk count < 2^16): hist stays 19.2 MB at
// NCHK=32. LDS atomics (R3 lesson: global atomics are 100us-class).
__global__ __launch_bounds__(512) void k_hist(
    const int* __restrict__ pd_src, const int* __restrict__ pd_dst,
    const int* __restrict__ dp_src, const int* __restrict__ dp_dst,
    uint16_t* __restrict__ hist){
  __shared__ uint32_t cnt[(N_P/HPH)/2];   // 12500 words = 50 KB
  const int b = blockIdx.x;
  const int arr = b >> 7, part = (b >> 5) & 3, chunk = b & 31;
  const int* src; int N; size_t hofs;
  switch(arr){
    case 0:  src = pd_src; N = N_P; hofs = HOFS_A0; break;
    case 1:  src = pd_dst; N = N_D; hofs = HOFS_A1; break;
    case 2:  src = dp_src; N = N_D; hofs = HOFS_A2; break;
    default: src = dp_dst; N = N_P; hofs = HOFS_A3; break;
  }
  const int PART = N / HPH;
  const int nw   = PART >> 1;
  const int lo   = part * PART;
  for (int i = threadIdx.x; i < nw; i += 512) cnt[i] = 0;
  __syncthreads();
  const int e0 = chunk*CHKE, e1 = min(e0 + CHKE, NE);
  const uint4* s4 = (const uint4*)(src + e0);
  const int n4 = (e1 - e0) >> 2;
  for (int i = threadIdx.x; i < n4; i += 512){
    uint4 v = s4[i];
    int a0 = (int)v.x - lo, a1 = (int)v.y - lo, a2 = (int)v.z - lo, a3 = (int)v.w - lo;
    if ((unsigned)a0 < (unsigned)PART) atomicAdd(&cnt[a0>>1], 1u << ((a0&1)<<4));
    if ((unsigned)a1 < (unsigned)PART) atomicAdd(&cnt[a1>>1], 1u << ((a1&1)<<4));
    if ((unsigned)a2 < (unsigned)PART) atomicAdd(&cnt[a2>>1], 1u << ((a2&1)<<4));
    if ((unsigned)a3 < (unsigned)PART) atomicAdd(&cnt[a3>>1], 1u << ((a3&1)<<4));
  }
  __syncthreads();
  // LDS word already packs nodes (2i, 2i+1) as u16 pair == global u16 layout
  uint32_t* out32 = (uint32_t*)(hist + hofs + (size_t)chunk*N + lo);
  for (int i = threadIdx.x; i < nw; i += 512) out32[i] = cnt[i];
}

// ---------------- phase 2: chunk-prefix (dst arrays) + degrees + rsqrt ------
// one thread per NODE PAIR (u32 = two packed u16 counts per chunk).
__global__ __launch_bounds__(512) void k_sumdeg(
    uint16_t* __restrict__ hist,
    int* __restrict__ cnt_d_in, int* __restrict__ cnt_p_in,
    float* __restrict__ rs_p_out, float* __restrict__ rs_p_in,
    float* __restrict__ rs_d_out, float* __restrict__ rs_d_in){
  const int gid = blockIdx.x*512 + threadIdx.x;
  if (gid >= (N_P + N_D)) return;          // 150000 pairs total
  int arr, pidx;
  if      (gid < N_P/2)        { arr = 0; pidx = gid; }
  else if (gid < N_P/2+N_D/2)  { arr = 1; pidx = gid - N_P/2; }
  else if (gid < N_P/2+N_D)    { arr = 2; pidx = gid - N_P/2 - N_D/2; }
  else                         { arr = 3; pidx = gid - N_P/2 - N_D; }
  int N; size_t hofs; bool pre;
  switch(arr){
    case 0:  N = N_P; hofs = HOFS_A0; pre = false; break;
    case 1:  N = N_D; hofs = HOFS_A1; pre = true;  break;
    case 2:  N = N_D; hofs = HOFS_A2; pre = false; break;
    default: N = N_P; hofs = HOFS_A3; pre = true;  break;
  }
  uint32_t* h32 = (uint32_t*)(hist + hofs) + pidx;
  const int stride = N >> 1;
  int run0 = 0, run1 = 0;
  if (pre){
    #pragma unroll 4
    for (int c = 0; c < NCHK; ++c){
      uint32_t w = h32[(size_t)c*stride];
      h32[(size_t)c*stride] = (uint32_t)run0 | ((uint32_t)run1 << 16);
      run0 += (int)(w & 0xffffu); run1 += (int)(w >> 16);
    }
  } else {
    #pragma unroll 4
    for (int c = 0; c < NCHK; ++c){
      uint32_t w = h32[(size_t)c*stride];
      run0 += (int)(w & 0xffffu); run1 += (int)(w >> 16);
    }
  }
  const int idx = 2*pidx;
  float rs0 = rsqrtf((float)max(run0, 1));
  float rs1 = rsqrtf((float)max(run1, 1));
  switch(arr){
    case 0:  rs_p_out[idx] = rs0; rs_p_out[idx+1] = rs1; break;
    case 1:  cnt_d_in[idx] = run0; cnt_d_in[idx+1] = run1;
             rs_d_in[idx] = rs0;  rs_d_in[idx+1] = rs1;  break;
    case 2:  rs_d_out[idx] = rs0; rs_d_out[idx+1] = rs1; break;
    default: cnt_p_in[idx] = run0; cnt_p_in[idx+1] = run1;
             rs_p_in[idx] = rs0;  rs_p_in[idx+1] = rs1;  break;
  }
}

// ---------------- hierarchical exclusive scan -------------------------------
__global__ void k_scan1(const int* __restrict__ cA, int nA,
                        const int* __restrict__ cB, int nB,
                        int* __restrict__ bsums, int nbA){
  __shared__ int red[8];
  int b = blockIdx.x, t = threadIdx.x;
  const int* in; int n, bi, slot;
  if (b < nbA){ in = cA; n = nA; bi = b;       slot = bi; }
  else        { in = cB; n = nB; bi = b - nbA; slot = 256 + bi; }
  int i = bi*512 + t;
  int v = (i < n) ? in[i] : 0;
  #pragma unroll
  for (int o = 32; o; o >>= 1) v += __shfl_down(v, o, 64);
  if ((t & 63) == 0) red[t >> 6] = v;
  __syncthreads();
  if (t == 0){ int s = 0; for (int k = 0; k < 8; ++k) s += red[k]; bsums[slot] = s; }
}

__global__ void k_scan2(int* bsums, int nbA, int nbB){
  __shared__ int sh[256];
  int seg = blockIdx.x, t = threadIdx.x;
  int nb = seg ? nbB : nbA;
  int* p = bsums + seg*256;
  int v = (t < nb) ? p[t] : 0;
  sh[t] = v; __syncthreads();
  for (int ofs = 1; ofs < 256; ofs <<= 1){
    int u = (t >= ofs) ? sh[t-ofs] : 0; __syncthreads();
    sh[t] += u; __syncthreads();
  }
  if (t < nb) p[t] = sh[t] - v;   // exclusive
}

__global__ void k_scan3(const int* __restrict__ cA, int nA,
                        const int* __restrict__ cB, int nB,
                        const int* __restrict__ bsums, int nbA,
                        int* __restrict__ offA, int* __restrict__ offB){
  __shared__ int sh[512];
  int b = blockIdx.x, t = threadIdx.x;
  const int* in; int n, bi; int* out; int base;
  if (b < nbA){ in = cA; n = nA; bi = b;       out = offA; base = bsums[bi]; }
  else        { in = cB; n = nB; bi = b - nbA; out = offB; base = bsums[256+bi]; }
  int i = bi*512 + t;
  int v = (i < n) ? in[i] : 0;
  sh[t] = v; __syncthreads();
  for (int ofs = 1; ofs < 512; ofs <<= 1){
    int u = (t >= ofs) ? sh[t-ofs] : 0; __syncthreads();
    sh[t] += u; __syncthreads();
  }
  if (i < n) out[i] = base + sh[t] - v;
  if (b == 0 && t == 0){ offA[nA] = NE; offB[nB] = NE; }
}

// ---------------- phase 3: scatter ------------------------------------------
// grid = 2*HPS*NCHK = 512 blocks x 512 thr. base[] doubles as the rank
// counter (LDS atomicAdd returns the write position). hist layout is
// [chunk][global node] so scatter's HPS=8 composes with hist's HPH=4.
__global__ __launch_bounds__(512) void k_scatter(
    const int* __restrict__ pd_src, const int* __restrict__ pd_dst,
    const int* __restrict__ dp_src, const int* __restrict__ dp_dst,
    const int* __restrict__ off_pd, const int* __restrict__ off_dp,
    const uint16_t* __restrict__ hist,
    int* __restrict__ col_pd, int* __restrict__ col_dp){
  __shared__ int base[N_P/HPS];   // 12500 ints = 50 KB
  const int b = blockIdx.x;
  const int gph = b >> 8, part = (b >> 5) & 7, chunk = b & 31;
  const int* dsts; const int* srcs; const int* off; int* col; int N; size_t hofs;
  if (gph == 0){ dsts = pd_dst; srcs = pd_src; off = off_pd; col = col_pd; N = N_D; hofs = HOFS_A1; }
  else         { dsts = dp_dst; srcs = dp_src; off = off_dp; col = col_dp; N = N_P; hofs = HOFS_A3; }
  const int PART = N / HPS;
  const int lo = part * PART;
  const uint32_t* hc32 = (const uint32_t*)(hist + hofs + (size_t)chunk*N + lo);
  const int* offp = off + lo;
  for (int i = threadIdx.x; i < (PART>>1); i += 512){
    uint32_t w = hc32[i];
    base[2*i]   = offp[2*i]   + (int)(w & 0xffffu);
    base[2*i+1] = offp[2*i+1] + (int)(w >> 16);
  }
  __syncthreads();
  const int e0 = chunk*CHKE, e1 = min(e0 + CHKE, NE);
  const uint4* d4 = (const uint4*)(dsts + e0);
  const int n4 = (e1 - e0) >> 2;
  for (int i = threadIdx.x; i < n4; i += 512){
    uint4 d = d4[i];
    int a0 = (int)d.x - lo, a1 = (int)d.y - lo, a2 = (int)d.z - lo, a3 = (int)d.w - lo;
    int e = e0 + 4*i;
    if ((unsigned)a0 < (unsigned)PART){ int p = atomicAdd(&base[a0], 1); col[p] = srcs[e+0]; }
    if ((unsigned)a1 < (unsigned)PART){ int p = atomicAdd(&base[a1], 1); col[p] = srcs[e+1]; }
    if ((unsigned)a2 < (unsigned)PART){ int p = atomicAdd(&base[a2], 1); col[p] = srcs[e+2]; }
    if ((unsigned)a3 < (unsigned)PART){ int p = atomicAdd(&base[a3], 1); col[p] = srcs[e+3]; }
  }
}

// ------ merged: W prep (blocks 0..5) + fp32->prescaled bf16 convert ---------
__global__ void k_convert(const float4* __restrict__ hp, const float4* __restrict__ hd,
                          const float* __restrict__ rs_po, const float* __restrict__ rs_do,
                          uint2* __restrict__ P0, uint2* __restrict__ D0,
                          const float* w0,const float* w1,const float* w2,
                          const float* w3,const float* w4,const float* w5,
                          uint16_t* __restrict__ wt,
                          uint16_t* z0, uint16_t* z1, uint16_t* z2,
                          uint16_t* z3, uint16_t* z4, uint16_t* z5){
  if (blockIdx.x < 6){
    int m = blockIdx.x;
    const float* W; uint16_t* Z;
    switch(m){ case 0:W=w0;Z=z0;break; case 1:W=w1;Z=z1;break; case 2:W=w2;Z=z2;break;
               case 3:W=w3;Z=z3;break; case 4:W=w4;Z=z4;break; default:W=w5;Z=z5; }
    uint16_t* T = wt + m*F*FP;
    for (int idx = threadIdx.x; idx < F*F; idx += 256){
      int k = idx >> 7, j = idx & 127;
      T[j*FP + k] = f2bf(W[idx]);
    }
    if (threadIdx.x < F) Z[threadIdx.x] = 0;   // sentinel zero row
    return;
  }
  int i = (blockIdx.x - 6)*256 + threadIdx.x;
  const int nP4 = N_P*F/4, nD4 = N_D*F/4;
  if (i < nP4){
    float4 v = hp[i]; float s = rs_po[i >> 5];
    uint2 r;
    r.x = ((uint32_t)f2bf(v.y*s)<<16) | f2bf(v.x*s);
    r.y = ((uint32_t)f2bf(v.w*s)<<16) | f2bf(v.z*s);
    P0[i] = r;
  } else {
    int j = i - nP4;
    if (j < nD4){
      float4 v = hd[j]; float s = rs_do[j >> 5];
      uint2 r;
      r.x = ((uint32_t)f2bf(v.y*s)<<16) | f2bf(v.x*s);
      r.y = ((uint32_t)f2bf(v.w*s)<<16) | f2bf(v.z*s);
      D0[j] = r;
    }
  }
}

// ---------------- fused gconv PAIR (R1/R4 proven form, reverted) ------------
// Gather: wave = 4 groups of 16 lanes; group g owns a row, lane l holds
// features [8l,8l+8). Broadcast all 16 col indices of the batch up front,
// issue ALL 8 (16 when deg>8) uint4 gather loads into explicit register
// arrays, THEN accumulate. (256,4) bounds; compiler settles at 64 VGPR.
// R8 reversion notes (counter-backed):
//  - NO non-temporal gather loads: nt raised FETCH 133->142 MB (lost L1/L2
//    reuse of popular src rows). Plain loads.
//  - NO LDS-staged epilogue: WRITE_SIZE 75000 KB is layer-3's LOGICAL fp32
//    output (top-5 rows are layer-3 dispatches); layers 1-2 were never
//    write-amplified. Direct stores.
//  - R2's dual-stream gather regressed (compiler serializes around extra
//    control flow) — do not re-add.
template<int OUT_MODE>
__global__ __launch_bounds__(256, 4) void k_gconv2(
    const uint16_t* __restrict__ xA, const int* __restrict__ offAp, const int* __restrict__ colA,
    const float* __restrict__ rsA, const uint16_t* __restrict__ WtA, const float* __restrict__ biasA,
    const float* __restrict__ rsnA, void* __restrict__ outA, int ndA, int nsA, int nblkA,
    const uint16_t* __restrict__ xB, const int* __restrict__ offBp, const int* __restrict__ colB,
    const float* __restrict__ rsB, const uint16_t* __restrict__ WtB, const float* __restrict__ biasB,
    const float* __restrict__ rsnB, void* __restrict__ outB, int ndB, int nsB)
{
  __shared__ uint16_t m_lds[64*FP];    // 17408 B
  const int tid  = threadIdx.x;
  const int lane = tid & 63;
  const int wv   = tid >> 6;

  const uint16_t* x; const int* off; const int* col; const float* rs_in;
  const uint16_t* Wt; const float* bias; const float* rs_next; void* outp;
  int n_dst, zrow, bid;
  if ((int)blockIdx.x < nblkA){
    x = xA; off = offAp; col = colA; rs_in = rsA; Wt = WtA; bias = biasA;
    rs_next = rsnA; outp = outA; n_dst = ndA; zrow = nsA; bid = blockIdx.x;
  } else {
    x = xB; off = offBp; col = colB; rs_in = rsB; Wt = WtB; bias = biasB;
    rs_next = rsnB; outp = outB; n_dst = ndB; zrow = nsB; bid = blockIdx.x - nblkA;
  }

  // ---- aggregation ----
  const int row0 = bid*64 + wv*16;
  const int g    = lane >> 4;     // group
  const int l    = lane & 15;     // lane in group; features [8l, 8l+8)
  const uint16_t* xl = x + l*8;   // lane-fixed feature slice base

  int e0a[4], e1a[4], cva[4];
  #pragma unroll
  for (int i = 0; i < 4; ++i){
    int r = row0 + i*4 + g;
    bool rv = r < n_dst;
    e0a[i] = rv ? off[r]   : 0;
    e1a[i] = rv ? off[r+1] : 0;
  }
  #pragma unroll
  for (int i = 0; i < 4; ++i){
    int last = (e1a[i] > 0) ? e1a[i]-1 : 0;
    int idx  = e0a[i] + l;
    cva[i] = col[idx < e1a[i] ? idx : last];   // hoisted first batch (4 loads in flight)
  }

  #pragma unroll
  for (int i = 0; i < 4; ++i){
    int e0 = e0a[i], e1 = e1a[i];
    int cv = cva[i];
    float a0=0.f,a1=0.f,a2=0.f,a3=0.f,a4=0.f,a5=0.f,a6=0.f,a7=0.f;
    for (int e = e0; e < e1; e += 16){
      // prefetch next batch of col indices (clamped; harmless L1 re-read)
      int nidx = e + 16 + l;
      int ncv  = col[nidx < e1 ? nidx : e1-1];
      int cnt  = e1 - e;
      const bool more = (cnt > 8);
      // broadcast col indices for the whole batch up front (VALU/LDS only)
      int cb[16];
      #pragma unroll
      for (int q = 0; q < 8; ++q) cb[q] = __shfl(cv, g*16 + q, 64);
      if (more){
        #pragma unroll
        for (int q = 8; q < 16; ++q) cb[q] = __shfl(cv, g*16 + q, 64);
      }
      // issue ALL gather loads before any accumulation (max MLP)
      uint4 u[8], w[8];
      #pragma unroll
      for (int q = 0; q < 8; ++q){
        int c = (q < cnt) ? cb[q] : zrow;        // sentinel row = zeros
        u[q] = *(const uint4*)(xl + (size_t)c*F);
      }
      if (more){
        #pragma unroll
        for (int q = 8; q < 16; ++q){
          int c = (q < cnt) ? cb[q] : zrow;
          w[q-8] = *(const uint4*)(xl + (size_t)c*F);
        }
      }
      // accumulate
      #pragma unroll
      for (int q = 0; q < 8; ++q){
        a0 += bf2f((uint16_t)u[q].x); a1 += bf2f((uint16_t)(u[q].x>>16));
        a2 += bf2f((uint16_t)u[q].y); a3 += bf2f((uint16_t)(u[q].y>>16));
        a4 += bf2f((uint16_t)u[q].z); a5 += bf2f((uint16_t)(u[q].z>>16));
        a6 += bf2f((uint16_t)u[q].w); a7 += bf2f((uint16_t)(u[q].w>>16));
      }
      if (more){
        #pragma unroll
        for (int q = 0; q < 8; ++q){
          a0 += bf2f((uint16_t)w[q].x); a1 += bf2f((uint16_t)(w[q].x>>16));
          a2 += bf2f((uint16_t)w[q].y); a3 += bf2f((uint16_t)(w[q].y>>16));
          a4 += bf2f((uint16_t)w[q].z); a5 += bf2f((uint16_t)(w[q].z>>16));
          a6 += bf2f((uint16_t)w[q].w); a7 += bf2f((uint16_t)(w[q].w>>16));
        }
      }
      cv = ncv;
    }
    int r = row0 + i*4 + g;
    float rs = (r < n_dst) ? rs_in[r] : 0.f;
    uint4 pk;
    pk.x = ((uint32_t)f2bf(a1*rs)<<16) | f2bf(a0*rs);
    pk.y = ((uint32_t)f2bf(a3*rs)<<16) | f2bf(a2*rs);
    pk.z = ((uint32_t)f2bf(a5*rs)<<16) | f2bf(a4*rs);
    pk.w = ((uint32_t)f2bf(a7*rs)<<16) | f2bf(a6*rs);
    *(uint4*)&m_lds[(wv*16 + i*4 + g)*FP + l*8] = pk;
  }
  // no barrier: m_lds rows are wave-private, same-wave ds ordering is implicit

  // ---- GEMM (operand-swapped): A = W^T tile, B = aggregated rows ----
  f32x4 acc[8];
  #pragma unroll
  for (int t = 0; t < 8; ++t) acc[t] = (f32x4){0.f,0.f,0.f,0.f};
  const int mrow = lane & 15;
  const int kgrp = lane >> 4;
  #pragma unroll
  for (int k0 = 0; k0 < F; k0 += 32){
    bf16x8 bfrag = *(const bf16x8*)&m_lds[(wv*16 + mrow)*FP + k0 + kgrp*8];
    #pragma unroll
    for (int t = 0; t < 8; ++t){
      bf16x8 afrag = *(const bf16x8*)&Wt[(t*16 + mrow)*FP + k0 + kgrp*8];
      acc[t] = __builtin_amdgcn_mfma_f32_16x16x32_bf16(afrag, bfrag, acc[t], 0, 0, 0);
    }
  }

  // ---- epilogue: lane owns dst-row rr, cols t*16 + quad*4 + (0..3) ----
  const int q4 = kgrp * 4;
  const int rr = row0 + mrow;
  if (rr < n_dst){
    float rsn = (OUT_MODE == 0) ? rs_next[rr] : 1.f;
    #pragma unroll
    for (int t = 0; t < 8; ++t){
      float4 b4 = *(const float4*)&bias[t*16 + q4];
      float v0 = fmaxf(acc[t][0] + b4.x, 0.f);
      float v1 = fmaxf(acc[t][1] + b4.y, 0.f);
      float v2 = fmaxf(acc[t][2] + b4.z, 0.f);
      float v3 = fmaxf(acc[t][3] + b4.w, 0.f);
      if (OUT_MODE == 0){
        uint2 pk;
        pk.x = ((uint32_t)f2bf(v1*rsn)<<16) | f2bf(v0*rsn);
        pk.y = ((uint32_t)f2bf(v3*rsn)<<16) | f2bf(v2*rsn);
        *(uint2*)((uint16_t*)outp + (size_t)rr*F + t*16 + q4) = pk;
      } else {
        float4 o; o.x = v0; o.y = v1; o.z = v2; o.w = v3;
        *(float4*)((float*)outp + (size_t)rr*F + t*16 + q4) = o;
      }
    }
  }
}

extern "C" void kernel_launch(void* const* d_in, const int* in_sizes, int n_in,
                              void* d_out, int out_size, void* d_ws, size_t ws_size,
                              hipStream_t stream) {
  const float* h_p   = (const float*)d_in[0];
  const float* h_d   = (const float*)d_in[1];
  const int* pd_src  = (const int*)d_in[2];
  const int* pd_dst  = (const int*)d_in[3];
  const int* dp_src  = (const int*)d_in[4];
  const int* dp_dst  = (const int*)d_in[5];
  const float* W1_pd = (const float*)d_in[6];   const float* b1_pd = (const float*)d_in[7];
  const float* W1_dp = (const float*)d_in[8];   const float* b1_dp = (const float*)d_in[9];
  const float* W2_pd = (const float*)d_in[10];  const float* b2_pd = (const float*)d_in[11];
  const float* W2_dp = (const float*)d_in[12];  const float* b2_dp = (const float*)d_in[13];
  const float* W3_pd = (const float*)d_in[14];  const float* b3_pd = (const float*)d_in[15];
  const float* W3_dp = (const float*)d_in[16];  const float* b3_dp = (const float*)d_in[17];

  char* w = (char*)d_ws;
  size_t o = 0;
  auto take = [&](size_t bytes)->char*{
    char* p = w + o; o += (bytes + 255) & ~(size_t)255; return p;
  };

  int* cnt_d_in  = (int*)take(4*(size_t)N_D);
  int* cnt_p_in  = (int*)take(4*(size_t)N_P);
  int* off_pd   = (int*)take(4*(size_t)(N_D+1));
  int* off_dp   = (int*)take(4*(size_t)(N_P+1));
  int* bsums    = (int*)take(4*512);
  int* col_pd   = (int*)take(4*(size_t)NE);
  int* col_dp   = (int*)take(4*(size_t)NE);
  float* rs_p_out = (float*)take(4*(size_t)N_P);
  float* rs_p_in  = (float*)take(4*(size_t)N_P);
  float* rs_d_out = (float*)take(4*(size_t)N_D);
  float* rs_d_in  = (float*)take(4*(size_t)N_D);
  uint16_t* wt  = (uint16_t*)take(2*(size_t)6*F*FP);
  // feature buffers have n+1 rows; row n is the zeroed sentinel
  uint16_t* P0  = (uint16_t*)take(2*(size_t)(N_P+1)*F);
  uint16_t* P1  = (uint16_t*)take(2*(size_t)(N_P+1)*F);
  uint16_t* P2  = (uint16_t*)take(2*(size_t)(N_P+1)*F);
  uint16_t* D0  = (uint16_t*)take(2*(size_t)(N_D+1)*F);
  uint16_t* D1  = (uint16_t*)take(2*(size_t)(N_D+1)*F);
  uint16_t* D2  = (uint16_t*)take(2*(size_t)(N_D+1)*F);

  // hist (u16, 19.2 MB) aliases P1 (25.6 MB): dead until k_convert/gconv,
  // which run strictly after k_scatter on the same stream.
  uint16_t* hist = P1;

  k_hist<<<4*HPH*NCHK, 512, 0, stream>>>(pd_src, pd_dst, dp_src, dp_dst, hist);
  k_sumdeg<<<((N_P+N_D) + 511)/512, 512, 0, stream>>>(
      hist, cnt_d_in, cnt_p_in, rs_p_out, rs_p_in, rs_d_out, rs_d_in);
  const int nbA = (N_D + 511)/512;   // 98
  const int nbB = (N_P + 511)/512;   // 196
  k_scan1<<<nbA+nbB, 512, 0, stream>>>(cnt_d_in, N_D, cnt_p_in, N_P, bsums, nbA);
  k_scan2<<<2, 256, 0, stream>>>(bsums, nbA, nbB);
  k_scan3<<<nbA+nbB, 512, 0, stream>>>(cnt_d_in, N_D, cnt_p_in, N_P, bsums, nbA, off_pd, off_dp);
  k_scatter<<<2*HPS*NCHK, 512, 0, stream>>>(pd_src, pd_dst, dp_src, dp_dst,
                                            off_pd, off_dp, hist, col_pd, col_dp);
  k_convert<<<CVT_TOT, 256, 0, stream>>>(
      (const float4*)h_p, (const float4*)h_d, rs_p_out, rs_d_out, (uint2*)P0, (uint2*)D0,
      W1_pd, W1_dp, W2_pd, W2_dp, W3_pd, W3_dp, wt,
      P0 + (size_t)N_P*F, D0 + (size_t)N_D*F,
      P1 + (size_t)N_P*F, D1 + (size_t)N_D*F,
      P2 + (size_t)N_P*F, D2 + (size_t)N_D*F);

  const int gd = (N_D + 63)/64, gp = (N_P + 63)/64;
  // layer 1 (both directions fused in one dispatch)
  k_gconv2<0><<<gd+gp, 256, 0, stream>>>(
      P0, off_pd, col_pd, rs_d_in, wt + 0*F*FP, b1_pd, rs_d_out, D1, N_D, N_P, gd,
      D0, off_dp, col_dp, rs_p_in, wt + 1*F*FP, b1_dp, rs_p_out, P1, N_P, N_D);
  // layer 2
  k_gconv2<0><<<gd+gp, 256, 0, stream>>>(
      P1, off_pd, col_pd, rs_d_in, wt + 2*F*FP, b2_pd, rs_d_out, D2, N_D, N_P, gd,
      D1, off_dp, col_dp, rs_p_in, wt + 3*F*FP, b2_dp, rs_p_out, P2, N_P, N_D);
  // layer 3 (fp32 outputs: h_p3 first, then h_d3)
  k_gconv2<1><<<gd+gp, 256, 0, stream>>>(
      P2, off_pd, col_pd, rs_d_in, wt + 4*F*FP, b3_pd, nullptr, (float*)d_out + (size_t)N_P*F, N_D, N_P, gd,
      D2, off_dp, col_dp, rs_p_in, wt + 5*F*FP, b3_dp, nullptr, (float*)d_out, N_P, N_D);
}

// Round 10
// 432.908 us; speedup vs baseline: 1.7165x; 1.0024x over previous
//
#include <hip/hip_runtime.h>
#include <stdint.h>

#define N_P 100000
#define N_D 50000
#define NE  600000
#define F   128
#define FP  136   // padded LDS/global row stride (272B = 17*16B: 16B-aligned, 2-way-free banks)

// counting-sort build params (u16 global hist, NCHK=32, HPH=4)
#define NCHK   32
#define CHKE   18752                 // edges per chunk (mult of 4); last chunk = 18688
#define HPH    4                     // hist partitions (u16-packed LDS -> 50 KB)
#define HPS    8                     // scatter partitions (int cursors -> 50 KB LDS)
// hist layout (u16 elements): A0 pd_src[32][N_P] | A1 pd_dst[32][N_D] | A2 dp_src[32][N_D] | A3 dp_dst[32][N_P]
#define HOFS_A0 ((size_t)0)
#define HOFS_A1 ((size_t)NCHK*N_P)
#define HOFS_A2 ((size_t)NCHK*N_P + (size_t)NCHK*N_D)
#define HOFS_A3 ((size_t)NCHK*N_P + (size_t)2*NCHK*N_D)
// convert work units ("blocks" of 256 threads)
#define CVT_TOT (6 + (N_P+N_D)*F/4/256)   // 6 + 18750 = 18756
#define NBA 98    // scan tiles over N_D (512 nodes each)
#define NBB 196   // scan tiles over N_P
// sumdeg tiling: 256 node-pairs (=512 nodes) per block, 4 arrays
#define SD_T0 196  // arr0 (N_P) tiles
#define SD_T1 98   // arr1 (N_D)
#define SD_T2 98   // arr2 (N_D)
#define SD_T3 196  // arr3 (N_P)
#define NSCAT 512  // scatter blocks in fused scatter+convert launch

typedef __attribute__((ext_vector_type(8))) __bf16 bf16x8;
typedef __attribute__((ext_vector_type(4))) float  f32x4;

static __device__ __forceinline__ float bf2f(uint16_t u){
  union{float f;uint32_t i;} v; v.i = ((uint32_t)u)<<16; return v.f;
}
static __device__ __forceinline__ uint16_t f2bf(float f){
  union{float f;uint32_t i;} v; v.f = f;
  uint32_t i = v.i;
  uint32_t r = i + 0x7fffu + ((i>>16)&1u);   // round-to-nearest-even
  return (uint16_t)(r>>16);
}

// ---------------- phase 1: per-(array, part, chunk) LDS histogram -----------
// grid = 4*HPH*NCHK = 512 blocks x 512 thr. u16-packed counts in LDS AND in
// global (per-chunk count < 2^16). LDS atomics (R3: global atomics 100us).
__global__ __launch_bounds__(512) void k_hist(
    const int* __restrict__ pd_src, const int* __restrict__ pd_dst,
    const int* __restrict__ dp_src, const int* __restrict__ dp_dst,
    uint16_t* __restrict__ hist){
  __shared__ uint32_t cnt[(N_P/HPH)/2];   // 12500 words = 50 KB
  const int b = blockIdx.x;
  const int arr = b >> 7, part = (b >> 5) & 3, chunk = b & 31;
  const int* src; int N; size_t hofs;
  switch(arr){
    case 0:  src = pd_src; N = N_P; hofs = HOFS_A0; break;
    case 1:  src = pd_dst; N = N_D; hofs = HOFS_A1; break;
    case 2:  src = dp_src; N = N_D; hofs = HOFS_A2; break;
    default: src = dp_dst; N = N_P; hofs = HOFS_A3; break;
  }
  const int PART = N / HPH;
  const int nw   = PART >> 1;
  const int lo   = part * PART;
  for (int i = threadIdx.x; i < nw; i += 512) cnt[i] = 0;
  __syncthreads();
  const int e0 = chunk*CHKE, e1 = min(e0 + CHKE, NE);
  const uint4* s4 = (const uint4*)(src + e0);
  const int n4 = (e1 - e0) >> 2;
  for (int i = threadIdx.x; i < n4; i += 512){
    uint4 v = s4[i];
    int a0 = (int)v.x - lo, a1 = (int)v.y - lo, a2 = (int)v.z - lo, a3 = (int)v.w - lo;
    if ((unsigned)a0 < (unsigned)PART) atomicAdd(&cnt[a0>>1], 1u << ((a0&1)<<4));
    if ((unsigned)a1 < (unsigned)PART) atomicAdd(&cnt[a1>>1], 1u << ((a1&1)<<4));
    if ((unsigned)a2 < (unsigned)PART) atomicAdd(&cnt[a2>>1], 1u << ((a2&1)<<4));
    if ((unsigned)a3 < (unsigned)PART) atomicAdd(&cnt[a3>>1], 1u << ((a3&1)<<4));
  }
  __syncthreads();
  uint32_t* out32 = (uint32_t*)(hist + hofs + (size_t)chunk*N + lo);
  for (int i = threadIdx.x; i < nw; i += 512) out32[i] = cnt[i];
}

// ------- phase 2 (R9): sumdeg + rs + FUSED scan1 (per-tile sums) ------------
// one block per 256 node-pairs (=512 nodes) of one array; block == scan tile,
// so the in-degree tile sums reduce directly into bsums (kills scan1 launch).
__global__ __launch_bounds__(256) void k_sumdeg2(
    uint16_t* __restrict__ hist,
    int* __restrict__ cnt_d_in, int* __restrict__ cnt_p_in,
    float* __restrict__ rs_p_out, float* __restrict__ rs_p_in,
    float* __restrict__ rs_d_out, float* __restrict__ rs_d_in,
    int* __restrict__ bsums){
  __shared__ int red[4];
  const int b = blockIdx.x, t = threadIdx.x;
  int arr, tile;
  if      (b < SD_T0)            { arr = 0; tile = b; }
  else if (b < SD_T0+SD_T1)      { arr = 1; tile = b - SD_T0; }
  else if (b < SD_T0+SD_T1+SD_T2){ arr = 2; tile = b - SD_T0 - SD_T1; }
  else                           { arr = 3; tile = b - SD_T0 - SD_T1 - SD_T2; }
  int N; size_t hofs; bool pre;
  switch(arr){
    case 0:  N = N_P; hofs = HOFS_A0; pre = false; break;
    case 1:  N = N_D; hofs = HOFS_A1; pre = true;  break;
    case 2:  N = N_D; hofs = HOFS_A2; pre = false; break;
    default: N = N_P; hofs = HOFS_A3; pre = true;  break;
  }
  const int npair = N >> 1;
  const int pidx  = tile*256 + t;
  int run0 = 0, run1 = 0;
  if (pidx < npair){
    uint32_t* h32 = (uint32_t*)(hist + hofs) + pidx;
    const int stride = npair;
    if (pre){
      #pragma unroll 4
      for (int c = 0; c < NCHK; ++c){
        uint32_t w = h32[(size_t)c*stride];
        h32[(size_t)c*stride] = (uint32_t)run0 | ((uint32_t)run1 << 16);
        run0 += (int)(w & 0xffffu); run1 += (int)(w >> 16);
      }
    } else {
      #pragma unroll 4
      for (int c = 0; c < NCHK; ++c){
        uint32_t w = h32[(size_t)c*stride];
        run0 += (int)(w & 0xffffu); run1 += (int)(w >> 16);
      }
    }
    const int idx = 2*pidx;
    float rs0 = rsqrtf((float)max(run0, 1));
    float rs1 = rsqrtf((float)max(run1, 1));
    switch(arr){
      case 0:  rs_p_out[idx] = rs0; rs_p_out[idx+1] = rs1; break;
      case 1:  cnt_d_in[idx] = run0; cnt_d_in[idx+1] = run1;
               rs_d_in[idx] = rs0;  rs_d_in[idx+1] = rs1;  break;
      case 2:  rs_d_out[idx] = rs0; rs_d_out[idx+1] = rs1; break;
      default: cnt_p_in[idx] = run0; cnt_p_in[idx+1] = run1;
               rs_p_in[idx] = rs0;  rs_p_in[idx+1] = rs1;  break;
    }
  }
  if (arr == 1 || arr == 3){
    int s = run0 + run1;               // 0 for out-of-range pairs
    #pragma unroll
    for (int o = 32; o; o >>= 1) s += __shfl_down(s, o, 64);
    if ((t & 63) == 0) red[t >> 6] = s;
    __syncthreads();
    if (t == 0){
      int tot = red[0] + red[1] + red[2] + red[3];
      bsums[(arr == 1) ? tile : 256 + tile] = tot;
    }
  }
}

// ------- scan3 (R9): inline scan2 (each block scans bsums seg in LDS) -------
__global__ __launch_bounds__(512) void k_scan3b(
    const int* __restrict__ cA, int nA,
    const int* __restrict__ cB, int nB,
    const int* __restrict__ bsums,
    int* __restrict__ offA, int* __restrict__ offB){
  __shared__ int sh[512];
  __shared__ int sb[256];
  __shared__ int base_s;
  int b = blockIdx.x, t = threadIdx.x;
  const int* in; int n, bi; int* out; int seg, nb;
  if (b < NBA){ in = cA; n = nA; bi = b;       out = offA; seg = 0; nb = NBA; }
  else        { in = cB; n = nB; bi = b - NBA; out = offB; seg = 1; nb = NBB; }
  // inline inclusive scan of the bsums segment (<=256 elems); bsums unmodified
  int v0 = 0;
  if (t < 256){ v0 = (t < nb) ? bsums[seg*256 + t] : 0; sb[t] = v0; }
  __syncthreads();
  for (int ofs = 1; ofs < 256; ofs <<= 1){
    int u = 0;
    if (t < 256 && t >= ofs) u = sb[t-ofs];
    __syncthreads();
    if (t < 256) sb[t] += u;
    __syncthreads();
  }
  if (t == 0) base_s = (bi == 0) ? 0 : sb[bi-1];   // exclusive prefix
  __syncthreads();
  const int base = base_s;
  // 512-wide tile scan
  int i = bi*512 + t;
  int v = (i < n) ? in[i] : 0;
  sh[t] = v; __syncthreads();
  for (int ofs = 1; ofs < 512; ofs <<= 1){
    int u = (t >= ofs) ? sh[t-ofs] : 0; __syncthreads();
    sh[t] += u; __syncthreads();
  }
  if (i < n) out[i] = base + sh[t] - v;
  if (b == 0 && t == 0){ offA[nA] = NE; offB[nB] = NE; }
}

// ---- convert work unit: ob<6 = weight transpose + sentinel; else features ----
static __device__ __forceinline__ void convert_ob(
    int ob, int t,
    const float4* __restrict__ hp, const float4* __restrict__ hd,
    const float* __restrict__ rs_po, const float* __restrict__ rs_do,
    uint2* __restrict__ P0, uint2* __restrict__ D0,
    const float* w0,const float* w1,const float* w2,
    const float* w3,const float* w4,const float* w5,
    uint16_t* __restrict__ wt,
    uint16_t* z0, uint16_t* z1, uint16_t* z2,
    uint16_t* z3, uint16_t* z4, uint16_t* z5)
{
  if (ob < 6){
    const float* W; uint16_t* Z;
    switch(ob){ case 0:W=w0;Z=z0;break; case 1:W=w1;Z=z1;break; case 2:W=w2;Z=z2;break;
                case 3:W=w3;Z=z3;break; case 4:W=w4;Z=z4;break; default:W=w5;Z=z5; }
    uint16_t* T = wt + ob*F*FP;
    for (int idx = t; idx < F*F; idx += 256){
      int k = idx >> 7, j = idx & 127;
      T[j*FP + k] = f2bf(W[idx]);
    }
    if (t < F) Z[t] = 0;   // sentinel zero row
    return;
  }
  int i = (ob - 6)*256 + t;
  const int nP4 = N_P*F/4, nD4 = N_D*F/4;
  if (i < nP4){
    float4 v = hp[i]; float s = rs_po[i >> 5];
    uint2 r;
    r.x = ((uint32_t)f2bf(v.y*s)<<16) | f2bf(v.x*s);
    r.y = ((uint32_t)f2bf(v.w*s)<<16) | f2bf(v.z*s);
    P0[i] = r;
  } else {
    int j = i - nP4;
    if (j < nD4){
      float4 v = hd[j]; float s = rs_do[j >> 5];
      uint2 r;
      r.x = ((uint32_t)f2bf(v.y*s)<<16) | f2bf(v.x*s);
      r.y = ((uint32_t)f2bf(v.w*s)<<16) | f2bf(v.z*s);
      D0[j] = r;
    }
  }
}

// ------- phase 3 (R9): scatter FUSED with convert (independent work) --------
// blocks [0,NSCAT): scatter (LDS cursors). blocks >= NSCAT: convert (2 ob
// units per 512-thr block). Convert fills the machine while the 512 scatter
// blocks run -> kills the separate convert launch + its gap.
__global__ __launch_bounds__(512) void k_scatter_cvt(
    const int* __restrict__ pd_src, const int* __restrict__ pd_dst,
    const int* __restrict__ dp_src, const int* __restrict__ dp_dst,
    const int* __restrict__ off_pd, const int* __restrict__ off_dp,
    const uint16_t* __restrict__ hist,
    int* __restrict__ col_pd, int* __restrict__ col_dp,
    const float4* __restrict__ hp, const float4* __restrict__ hd,
    const float* __restrict__ rs_po, const float* __restrict__ rs_do,
    uint2* __restrict__ P0, uint2* __restrict__ D0,
    const float* w0,const float* w1,const float* w2,
    const float* w3,const float* w4,const float* w5,
    uint16_t* __restrict__ wt,
    uint16_t* z0, uint16_t* z1, uint16_t* z2,
    uint16_t* z3, uint16_t* z4, uint16_t* z5){
  __shared__ int base[N_P/HPS];   // 12500 ints = 50 KB (scatter blocks only)
  const int b = blockIdx.x;
  if (b >= NSCAT){
    const int ob = (b - NSCAT)*2 + (threadIdx.x >> 8);
    if (ob < CVT_TOT)
      convert_ob(ob, threadIdx.x & 255, hp, hd, rs_po, rs_do, P0, D0,
                 w0,w1,w2,w3,w4,w5, wt, z0,z1,z2,z3,z4,z5);
    return;
  }
  const int gph = b >> 8, part = (b >> 5) & 7, chunk = b & 31;
  const int* dsts; const int* srcs; const int* off; int* col; int N; size_t hofs;
  if (gph == 0){ dsts = pd_dst; srcs = pd_src; off = off_pd; col = col_pd; N = N_D; hofs = HOFS_A1; }
  else         { dsts = dp_dst; srcs = dp_src; off = off_dp; col = col_dp; N = N_P; hofs = HOFS_A3; }
  const int PART = N / HPS;
  const int lo = part * PART;
  const uint32_t* hc32 = (const uint32_t*)(hist + hofs + (size_t)chunk*N + lo);
  const int* offp = off + lo;
  for (int i = threadIdx.x; i < (PART>>1); i += 512){
    uint32_t w = hc32[i];
    base[2*i]   = offp[2*i]   + (int)(w & 0xffffu);
    base[2*i+1] = offp[2*i+1] + (int)(w >> 16);
  }
  __syncthreads();
  const int e0 = chunk*CHKE, e1 = min(e0 + CHKE, NE);
  const uint4* d4 = (const uint4*)(dsts + e0);
  const int n4 = (e1 - e0) >> 2;
  for (int i = threadIdx.x; i < n4; i += 512){
    uint4 d = d4[i];
    int a0 = (int)d.x - lo, a1 = (int)d.y - lo, a2 = (int)d.z - lo, a3 = (int)d.w - lo;
    int e = e0 + 4*i;
    if ((unsigned)a0 < (unsigned)PART){ int p = atomicAdd(&base[a0], 1); col[p] = srcs[e+0]; }
    if ((unsigned)a1 < (unsigned)PART){ int p = atomicAdd(&base[a1], 1); col[p] = srcs[e+1]; }
    if ((unsigned)a2 < (unsigned)PART){ int p = atomicAdd(&base[a2], 1); col[p] = srcs[e+2]; }
    if ((unsigned)a3 < (unsigned)PART){ int p = atomicAdd(&base[a3], 1); col[p] = srcs[e+3]; }
  }
}

// ---------------- fused gconv PAIR (R1/R4 gather, R9 2-pass GEMM) -----------
// Gather: wave = 4 groups of 16 lanes; group g owns a row, lane l holds
// features [8l,8l+8). Broadcast all 16 col indices up front, issue ALL 8
// (16 when deg>8) plain uint4 gather loads into register arrays, THEN
// accumulate. (256,4) bounds. Counter-backed reversions: no nt loads (FETCH
// +9MB), no LDS epilogue (WRITE 75MB = layer-3 logical), no dual-stream.
// R9: GEMM split into 2 passes of 4 acc tiles with per-pass epilogue
// (#pragma unroll 1) — halves live AGPRs (32->16). Theory: occupancy 33% is
// unified VGPR+AGPR-capped (~2.7 waves/SIMD); halving AGPR should raise
// resident waves for the latency-bound gather phase.
template<int OUT_MODE>
__global__ __launch_bounds__(256, 4) void k_gconv2(
    const uint16_t* __restrict__ xA, const int* __restrict__ offAp, const int* __restrict__ colA,
    const float* __restrict__ rsA, const uint16_t* __restrict__ WtA, const float* __restrict__ biasA,
    const float* __restrict__ rsnA, void* __restrict__ outA, int ndA, int nsA, int nblkA,
    const uint16_t* __restrict__ xB, const int* __restrict__ offBp, const int* __restrict__ colB,
    const float* __restrict__ rsB, const uint16_t* __restrict__ WtB, const float* __restrict__ biasB,
    const float* __restrict__ rsnB, void* __restrict__ outB, int ndB, int nsB)
{
  __shared__ uint16_t m_lds[64*FP];    // 17408 B
  const int tid  = threadIdx.x;
  const int lane = tid & 63;
  const int wv   = tid >> 6;

  const uint16_t* x; const int* off; const int* col; const float* rs_in;
  const uint16_t* Wt; const float* bias; const float* rs_next; void* outp;
  int n_dst, zrow, bid;
  if ((int)blockIdx.x < nblkA){
    x = xA; off = offAp; col = colA; rs_in = rsA; Wt = WtA; bias = biasA;
    rs_next = rsnA; outp = outA; n_dst = ndA; zrow = nsA; bid = blockIdx.x;
  } else {
    x = xB; off = offBp; col = colB; rs_in = rsB; Wt = WtB; bias = biasB;
    rs_next = rsnB; outp = outB; n_dst = ndB; zrow = nsB; bid = blockIdx.x - nblkA;
  }

  // ---- aggregation ----
  const int row0 = bid*64 + wv*16;
  const int g    = lane >> 4;     // group
  const int l    = lane & 15;     // lane in group; features [8l, 8l+8)
  const uint16_t* xl = x + l*8;   // lane-fixed feature slice base

  int e0a[4], e1a[4], cva[4];
  #pragma unroll
  for (int i = 0; i < 4; ++i){
    int r = row0 + i*4 + g;
    bool rv = r < n_dst;
    e0a[i] = rv ? off[r]   : 0;
    e1a[i] = rv ? off[r+1] : 0;
  }
  #pragma unroll
  for (int i = 0; i < 4; ++i){
    int last = (e1a[i] > 0) ? e1a[i]-1 : 0;
    int idx  = e0a[i] + l;
    cva[i] = col[idx < e1a[i] ? idx : last];   // hoisted first batch (4 loads in flight)
  }

  #pragma unroll
  for (int i = 0; i < 4; ++i){
    int e0 = e0a[i], e1 = e1a[i];
    int cv = cva[i];
    float a0=0.f,a1=0.f,a2=0.f,a3=0.f,a4=0.f,a5=0.f,a6=0.f,a7=0.f;
    for (int e = e0; e < e1; e += 16){
      // prefetch next batch of col indices (clamped; harmless L1 re-read)
      int nidx = e + 16 + l;
      int ncv  = col[nidx < e1 ? nidx : e1-1];
      int cnt  = e1 - e;
      const bool more = (cnt > 8);
      // broadcast col indices for the whole batch up front (VALU/LDS only)
      int cb[16];
      #pragma unroll
      for (int q = 0; q < 8; ++q) cb[q] = __shfl(cv, g*16 + q, 64);
      if (more){
        #pragma unroll
        for (int q = 8; q < 16; ++q) cb[q] = __shfl(cv, g*16 + q, 64);
      }
      // issue ALL gather loads before any accumulation (max MLP)
      uint4 u[8], w[8];
      #pragma unroll
      for (int q = 0; q < 8; ++q){
        int c = (q < cnt) ? cb[q] : zrow;        // sentinel row = zeros
        u[q] = *(const uint4*)(xl + (size_t)c*F);
      }
      if (more){
        #pragma unroll
        for (int q = 8; q < 16; ++q){
          int c = (q < cnt) ? cb[q] : zrow;
          w[q-8] = *(const uint4*)(xl + (size_t)c*F);
        }
      }
      // accumulate
      #pragma unroll
      for (int q = 0; q < 8; ++q){
        a0 += bf2f((uint16_t)u[q].x); a1 += bf2f((uint16_t)(u[q].x>>16));
        a2 += bf2f((uint16_t)u[q].y); a3 += bf2f((uint16_t)(u[q].y>>16));
        a4 += bf2f((uint16_t)u[q].z); a5 += bf2f((uint16_t)(u[q].z>>16));
        a6 += bf2f((uint16_t)u[q].w); a7 += bf2f((uint16_t)(u[q].w>>16));
      }
      if (more){
        #pragma unroll
        for (int q = 0; q < 8; ++q){
          a0 += bf2f((uint16_t)w[q].x); a1 += bf2f((uint16_t)(w[q].x>>16));
          a2 += bf2f((uint16_t)w[q].y); a3 += bf2f((uint16_t)(w[q].y>>16));
          a4 += bf2f((uint16_t)w[q].z); a5 += bf2f((uint16_t)(w[q].z>>16));
          a6 += bf2f((uint16_t)w[q].w); a7 += bf2f((uint16_t)(w[q].w>>16));
        }
      }
      cv = ncv;
    }
    int r = row0 + i*4 + g;
    float rs = (r < n_dst) ? rs_in[r] : 0.f;
    uint4 pk;
    pk.x = ((uint32_t)f2bf(a1*rs)<<16) | f2bf(a0*rs);
    pk.y = ((uint32_t)f2bf(a3*rs)<<16) | f2bf(a2*rs);
    pk.z = ((uint32_t)f2bf(a5*rs)<<16) | f2bf(a4*rs);
    pk.w = ((uint32_t)f2bf(a7*rs)<<16) | f2bf(a6*rs);
    *(uint4*)&m_lds[(wv*16 + i*4 + g)*FP + l*8] = pk;
  }
  // no barrier: m_lds rows are wave-private, same-wave ds ordering is implicit

  // ---- GEMM (operand-swapped), 2 passes of 4 tiles to halve live AGPRs ----
  const int mrow = lane & 15;
  const int kgrp = lane >> 4;
  const int q4 = kgrp * 4;
  const int rr = row0 + mrow;
  const bool rv = rr < n_dst;
  const float rsn = (OUT_MODE == 0) ? (rv ? rs_next[rr] : 0.f) : 1.f;
  #pragma unroll 1
  for (int pass = 0; pass < 2; ++pass){
    f32x4 acc[4];
    #pragma unroll
    for (int t = 0; t < 4; ++t) acc[t] = (f32x4){0.f,0.f,0.f,0.f};
    #pragma unroll
    for (int k0 = 0; k0 < F; k0 += 32){
      bf16x8 bfrag = *(const bf16x8*)&m_lds[(wv*16 + mrow)*FP + k0 + kgrp*8];
      #pragma unroll
      for (int t = 0; t < 4; ++t){
        bf16x8 afrag = *(const bf16x8*)&Wt[((pass*4 + t)*16 + mrow)*FP + k0 + kgrp*8];
        acc[t] = __builtin_amdgcn_mfma_f32_16x16x32_bf16(afrag, bfrag, acc[t], 0, 0, 0);
      }
    }
    if (rv){
      #pragma unroll
      for (int t = 0; t < 4; ++t){
        const int tp = pass*4 + t;
        float4 b4 = *(const float4*)&bias[tp*16 + q4];
        float v0 = fmaxf(acc[t][0] + b4.x, 0.f);
        float v1 = fmaxf(acc[t][1] + b4.y, 0.f);
        float v2 = fmaxf(acc[t][2] + b4.z, 0.f);
        float v3 = fmaxf(acc[t][3] + b4.w, 0.f);
        if (OUT_MODE == 0){
          uint2 pk;
          pk.x = ((uint32_t)f2bf(v1*rsn)<<16) | f2bf(v0*rsn);
          pk.y = ((uint32_t)f2bf(v3*rsn)<<16) | f2bf(v2*rsn);
          *(uint2*)((uint16_t*)outp + (size_t)rr*F + tp*16 + q4) = pk;
        } else {
          float4 o; o.x = v0; o.y = v1; o.z = v2; o.w = v3;
          *(float4*)((float*)outp + (size_t)rr*F + tp*16 + q4) = o;
        }
      }
    }
  }
}

extern "C" void kernel_launch(void* const* d_in, const int* in_sizes, int n_in,
                              void* d_out, int out_size, void* d_ws, size_t ws_size,
                              hipStream_t stream) {
  const float* h_p   = (const float*)d_in[0];
  const float* h_d   = (const float*)d_in[1];
  const int* pd_src  = (const int*)d_in[2];
  const int* pd_dst  = (const int*)d_in[3];
  const int* dp_src  = (const int*)d_in[4];
  const int* dp_dst  = (const int*)d_in[5];
  const float* W1_pd = (const float*)d_in[6];   const float* b1_pd = (const float*)d_in[7];
  const float* W1_dp = (const float*)d_in[8];   const float* b1_dp = (const float*)d_in[9];
  const float* W2_pd = (const float*)d_in[10];  const float* b2_pd = (const float*)d_in[11];
  const float* W2_dp = (const float*)d_in[12];  const float* b2_dp = (const float*)d_in[13];
  const float* W3_pd = (const float*)d_in[14];  const float* b3_pd = (const float*)d_in[15];
  const float* W3_dp = (const float*)d_in[16];  const float* b3_dp = (const float*)d_in[17];

  char* w = (char*)d_ws;
  size_t o = 0;
  auto take = [&](size_t bytes)->char*{
    char* p = w + o; o += (bytes + 255) & ~(size_t)255; return p;
  };

  int* cnt_d_in  = (int*)take(4*(size_t)N_D);
  int* cnt_p_in  = (int*)take(4*(size_t)N_P);
  int* off_pd   = (int*)take(4*(size_t)(N_D+1));
  int* off_dp   = (int*)take(4*(size_t)(N_P+1));
  int* bsums    = (int*)take(4*512);
  int* col_pd   = (int*)take(4*(size_t)NE);
  int* col_dp   = (int*)take(4*(size_t)NE);
  float* rs_p_out = (float*)take(4*(size_t)N_P);
  float* rs_p_in  = (float*)take(4*(size_t)N_P);
  float* rs_d_out = (float*)take(4*(size_t)N_D);
  float* rs_d_in  = (float*)take(4*(size_t)N_D);
  uint16_t* wt  = (uint16_t*)take(2*(size_t)6*F*FP);
  // feature buffers have n+1 rows; row n is the zeroed sentinel
  uint16_t* P0  = (uint16_t*)take(2*(size_t)(N_P+1)*F);
  uint16_t* P1  = (uint16_t*)take(2*(size_t)(N_P+1)*F);
  uint16_t* P2  = (uint16_t*)take(2*(size_t)(N_P+1)*F);
  uint16_t* D0  = (uint16_t*)take(2*(size_t)(N_D+1)*F);
  uint16_t* D1  = (uint16_t*)take(2*(size_t)(N_D+1)*F);
  uint16_t* D2  = (uint16_t*)take(2*(size_t)(N_D+1)*F);

  // hist (u16, 19.2 MB) aliases P1 (25.6 MB): dead until convert/gconv, which
  // run strictly after scatter on the same stream. Convert's only P1 write is
  // the sentinel row at byte offset 25.6 MB — past the hist region.
  uint16_t* hist = P1;

  k_hist<<<4*HPH*NCHK, 512, 0, stream>>>(pd_src, pd_dst, dp_src, dp_dst, hist);
  k_sumdeg2<<<SD_T0+SD_T1+SD_T2+SD_T3, 256, 0, stream>>>(
      hist, cnt_d_in, cnt_p_in, rs_p_out, rs_p_in, rs_d_out, rs_d_in, bsums);
  k_scan3b<<<NBA+NBB, 512, 0, stream>>>(cnt_d_in, N_D, cnt_p_in, N_P, bsums, off_pd, off_dp);
  k_scatter_cvt<<<NSCAT + (CVT_TOT+1)/2, 512, 0, stream>>>(
      pd_src, pd_dst, dp_src, dp_dst, off_pd, off_dp, hist, col_pd, col_dp,
      (const float4*)h_p, (const float4*)h_d, rs_p_out, rs_d_out,
      (uint2*)P0, (uint2*)D0,
      W1_pd, W1_dp, W2_pd, W2_dp, W3_pd, W3_dp, wt,
      P0 + (size_t)N_P*F, D0 + (size_t)N_D*F,
      P1 + (size_t)N_P*F, D1 + (size_t)N_D*F,
      P2 + (size_t)N_P*F, D2 + (size_t)N_D*F);

  const int gd = (N_D + 63)/64, gp = (N_P + 63)/64;
  // layer 1 (both directions fused in one dispatch)
  k_gconv2<0><<<gd+gp, 256, 0, stream>>>(
      P0, off_pd, col_pd, rs_d_in, wt + 0*F*FP, b1_pd, rs_d_out, D1, N_D, N_P, gd,
      D0, off_dp, col_dp, rs_p_in, wt + 1*F*FP, b1_dp, rs_p_out, P1, N_P, N_D);
  // layer 2
  k_gconv2<0><<<gd+gp, 256, 0, stream>>>(
      P1, off_pd, col_pd, rs_d_in, wt + 2*F*FP, b2_pd, rs_d_out, D2, N_D, N_P, gd,
      D1, off_dp, col_dp, rs_p_in, wt + 3*F*FP, b2_dp, rs_p_out, P2, N_P, N_D);
  // layer 3 (fp32 outputs: h_p3 first, then h_d3)
  k_gconv2<1><<<gd+gp, 256, 0, stream>>>(
      P2, off_pd, col_pd, rs_d_in, wt + 4*F*FP, b3_pd, nullptr, (float*)d_out + (size_t)N_P*F, N_D, N_P, gd,
      D2, off_dp, col_dp, rs_p_in, wt + 5*F*FP, b3_dp, nullptr, (float*)d_out, N_P, N_D);
}